// Round 1
// baseline (654.303 us; speedup 1.0000x reference)
//
#include <hip/hip_runtime.h>
#include <hip/hip_bf16.h>
#include <stdint.h>

// Problem constants (from reference setup_inputs)
#define N_TOK 4096
#define DIM   1024
#define NE    8
#define NH    2048
#define NO    1024

typedef __attribute__((ext_vector_type(8))) short bf16x8;
typedef __attribute__((ext_vector_type(4))) float f32x4;

__device__ inline unsigned short f2bf(float f) {
    unsigned u = __float_as_uint(f);
    u += 0x7fffu + ((u >> 16) & 1u);   // round-to-nearest-even
    return (unsigned short)(u >> 16);
}

__device__ inline void async_copy16(const void* g, void* l) {
    __builtin_amdgcn_global_load_lds(
        (const __attribute__((address_space(1))) void*)g,
        (__attribute__((address_space(3))) void*)l, 16, 0, 0);
}

// ---------------- zero meta ----------------
__global__ void zero_meta_kernel(int* counts, float* importance) {
    int t = threadIdx.x;
    if (t < NE) { counts[t] = 0; importance[t] = 0.0f; }
}

// ---------------- fused layernorm + gating ----------------
// one block (256 thr) per token row
__global__ __launch_bounds__(256) void ln_gate_kernel(
    const float* __restrict__ x, const float* __restrict__ nw,
    const float* __restrict__ nb, const float* __restrict__ eps_p,
    const float* __restrict__ wg,
    unsigned short* __restrict__ xn_bf, unsigned short* __restrict__ x_bf,
    int* __restrict__ tok_e, float* __restrict__ tok_g,
    int* __restrict__ counts, float* __restrict__ importance)
{
    int n = blockIdx.x;
    int t = threadIdx.x;
    int lane = t & 63, wv = t >> 6;

    const float4 xv = ((const float4*)(x + (size_t)n * DIM))[t];
    float s  = xv.x + xv.y + xv.z + xv.w;
    float s2 = xv.x*xv.x + xv.y*xv.y + xv.z*xv.z + xv.w*xv.w;
    #pragma unroll
    for (int o = 32; o > 0; o >>= 1) {
        s  += __shfl_down(s, o);
        s2 += __shfl_down(s2, o);
    }
    __shared__ float rs[4], rs2[4];
    __shared__ float gred[4][NE];
    if (lane == 0) { rs[wv] = s; rs2[wv] = s2; }
    __syncthreads();
    float S  = rs[0] + rs[1] + rs[2] + rs[3];
    float S2 = rs2[0] + rs2[1] + rs2[2] + rs2[3];
    const float inv = 1.0f / (float)DIM;
    float mu = S * inv;
    float var = fmaxf(S2 * inv - mu * mu, 0.0f);   // biased, like F.layer_norm
    float rstd = rsqrtf(var + eps_p[0]);

    float4 w4 = ((const float4*)nw)[t];
    float4 b4 = ((const float4*)nb)[t];
    float xn0 = (xv.x - mu) * rstd * w4.x + b4.x;
    float xn1 = (xv.y - mu) * rstd * w4.y + b4.y;
    float xn2 = (xv.z - mu) * rstd * w4.z + b4.z;
    float xn3 = (xv.w - mu) * rstd * w4.w + b4.w;

    ushort4 pn; pn.x = f2bf(xn0); pn.y = f2bf(xn1); pn.z = f2bf(xn2); pn.w = f2bf(xn3);
    ((ushort4*)(xn_bf + (size_t)n * DIM))[t] = pn;
    ushort4 px; px.x = f2bf(xv.x); px.y = f2bf(xv.y); px.z = f2bf(xv.z); px.w = f2bf(xv.w);
    ((ushort4*)(x_bf + (size_t)n * DIM))[t] = px;

    // gating logits: x_norm (fp32) @ w_gate [D][E]
    float acc[NE];
    #pragma unroll
    for (int e = 0; e < NE; ++e) acc[e] = 0.0f;
    float xns[4] = {xn0, xn1, xn2, xn3};
    const float4* wgp = (const float4*)(wg + (size_t)(4 * t) * NE);
    #pragma unroll
    for (int j = 0; j < 4; ++j) {
        float4 w0 = wgp[2 * j], w1 = wgp[2 * j + 1];
        float xj = xns[j];
        acc[0] += xj * w0.x; acc[1] += xj * w0.y; acc[2] += xj * w0.z; acc[3] += xj * w0.w;
        acc[4] += xj * w1.x; acc[5] += xj * w1.y; acc[6] += xj * w1.z; acc[7] += xj * w1.w;
    }
    #pragma unroll
    for (int o = 32; o > 0; o >>= 1) {
        #pragma unroll
        for (int e = 0; e < NE; ++e) acc[e] += __shfl_down(acc[e], o);
    }
    if (lane == 0) {
        #pragma unroll
        for (int e = 0; e < NE; ++e) gred[wv][e] = acc[e];
    }
    __syncthreads();
    if (t == 0) {
        float lg[NE];
        float nrm2 = 0.0f;
        #pragma unroll
        for (int e = 0; e < NE; ++e) {
            lg[e] = gred[0][e] + gred[1][e] + gred[2][e] + gred[3][e];
            nrm2 += lg[e] * lg[e];
        }
        float den = fmaxf(sqrtf(nrm2), 1e-12f);
        float linv = 1.0f / den;
        #pragma unroll
        for (int e = 0; e < NE; ++e) lg[e] *= linv;
        float mx = lg[0];
        #pragma unroll
        for (int e = 1; e < NE; ++e) mx = fmaxf(mx, lg[e]);
        float p[NE], ps = 0.0f;
        #pragma unroll
        for (int e = 0; e < NE; ++e) { p[e] = expf(lg[e] - mx); ps += p[e]; }
        float pinv = 1.0f / ps;
        #pragma unroll
        for (int e = 0; e < NE; ++e) p[e] *= pinv;
        // top-2, lowest-index wins ties (jax.lax.top_k semantics)
        int i0 = 0; float b0 = lg[0];
        #pragma unroll
        for (int e = 1; e < NE; ++e) if (lg[e] > b0) { b0 = lg[e]; i0 = e; }
        int i1 = -1; float b1 = -3.0e38f;
        #pragma unroll
        for (int e = 0; e < NE; ++e) if (e != i0 && lg[e] > b1) { b1 = lg[e]; i1 = e; }
        float g0 = p[i0], g1 = p[i1];
        tok_e[2 * n] = i0; tok_e[2 * n + 1] = i1;
        tok_g[2 * n] = g0; tok_g[2 * n + 1] = g1;
        atomicAdd(&counts[i0], 1); atomicAdd(&counts[i1], 1);
        atomicAdd(&importance[i0], g0); atomicAdd(&importance[i1], g1);
    }
}

// ---------------- fp32 -> bf16 bulk convert ----------------
__global__ void cvt_bf16_kernel(const float* __restrict__ src,
                                unsigned short* __restrict__ dst, int n4) {
    int i = blockIdx.x * blockDim.x + threadIdx.x;
    if (i < n4) {
        float4 v = ((const float4*)src)[i];
        ushort4 o; o.x = f2bf(v.x); o.y = f2bf(v.y); o.z = f2bf(v.z); o.w = f2bf(v.w);
        ((ushort4*)dst)[i] = o;
    }
}

// ---------------- output_weight [D][O] -> bf16 [O][D] ----------------
__global__ void transpose_cvt_kernel(const float* __restrict__ w,
                                     unsigned short* __restrict__ wt) {
    __shared__ float tile[32][33];
    int tx = threadIdx.x, ty = threadIdx.y;
    int o0 = blockIdx.x * 32, d0 = blockIdx.y * 32;
    tile[ty][tx] = w[(size_t)(d0 + ty) * NO + o0 + tx];
    __syncthreads();
    wt[(size_t)(o0 + ty) * DIM + d0 + tx] = f2bf(tile[tx][ty]);
}

// ---------------- offsets + loss + gate_fraction ----------------
__device__ inline float cv_sq(const float* v) {
    float m = 0.0f;
    for (int e = 0; e < NE; ++e) m += v[e];
    m *= (1.0f / NE);
    float s = 0.0f;
    for (int e = 0; e < NE; ++e) { float d = v[e] - m; s += d * d; }
    s *= (1.0f / (NE - 1));          // ddof=1
    return s / (m * m + 1e-6f);
}

__global__ void finalize_kernel(const int* __restrict__ counts,
                                const float* __restrict__ imp,
                                int* __restrict__ offsets, int* __restrict__ cursor,
                                float* __restrict__ out_tail) {
    if (threadIdx.x != 0 || blockIdx.x != 0) return;
    float li[NE], ii[NE];
    int off = 0;
    for (int e = 0; e < NE; ++e) {
        offsets[e] = off; cursor[e] = off;
        off += counts[e];
        li[e] = (float)counts[e]; ii[e] = imp[e];
    }
    float tot = (float)off;
    out_tail[0] = 0.01f * (cv_sq(ii) + cv_sq(li));   // loss
    for (int e = 0; e < NE; ++e) out_tail[1 + e] = li[e] / tot;  // gate_fraction
}

// ---------------- scatter tokens into expert buckets ----------------
__global__ void scatter_kernel(const int* __restrict__ tok_e,
                               int* __restrict__ cursor,
                               int* __restrict__ rowsbuf, int* __restrict__ pair_slot) {
    int n = blockIdx.x * blockDim.x + threadIdx.x;
    if (n >= N_TOK) return;
    #pragma unroll
    for (int k = 0; k < 2; ++k) {
        int e = tok_e[2 * n + k];
        int slot = atomicAdd(&cursor[e], 1);   // cursor starts at offsets[e]
        rowsbuf[slot] = n;
        pair_slot[2 * n + k] = slot;
    }
}

// ---------------- GEMM common tile params ----------------
#define BM 128
#define BN 128
#define BK 64

// GEMM1: h[slot][col] = silu( xn[token] . wh[e][col] + bias ), bf16 out
__global__ __launch_bounds__(256) void gemm1_kernel(
    const unsigned short* __restrict__ xn,   // [N][D] bf16
    const unsigned short* __restrict__ wh,   // [E][H][D] bf16
    const float* __restrict__ hb,            // [E][H]
    const int* __restrict__ rowsbuf,
    const int* __restrict__ counts, const int* __restrict__ offsets,
    unsigned short* __restrict__ hbuf)       // [2N][H] bf16
{
    int e = blockIdx.z;
    int count = counts[e];
    int tm = blockIdx.y, tn = blockIdx.x;
    if (tm * BM >= count) return;
    int off = offsets[e];

    __shared__ alignas(16) short As[BM * BK];
    __shared__ alignas(16) short Bs[BN * BK];

    int t = threadIdx.x;
    int c = t & 7, rl = t >> 3;
    const unsigned short* aptr[4];
    const unsigned short* bptr[4];
    #pragma unroll
    for (int p = 0; p < 4; ++p) {
        int mrow = tm * BM + p * 32 + rl;
        int mc = mrow < count ? mrow : count - 1;
        int token = rowsbuf[off + mc];
        aptr[p] = xn + (size_t)token * DIM;
        int nrow = tn * BN + p * 32 + rl;
        bptr[p] = wh + ((size_t)e * NH + nrow) * DIM;
    }

    int lane = t & 63, wvi = t >> 6;
    int wm = (wvi & 1) * 64, wn = (wvi >> 1) * 64;
    int l15 = lane & 15, qk = (lane >> 4) * 8;

    f32x4 acc[4][4];
    #pragma unroll
    for (int i = 0; i < 4; ++i)
        #pragma unroll
        for (int j = 0; j < 4; ++j) acc[i][j] = (f32x4){0.f, 0.f, 0.f, 0.f};

    for (int kt = 0; kt < DIM / BK; ++kt) {
        int kb = kt * BK + c * 8;
        #pragma unroll
        for (int p = 0; p < 4; ++p)
            async_copy16(aptr[p] + kb, (char*)As + p * 4096 + t * 16);
        #pragma unroll
        for (int p = 0; p < 4; ++p)
            async_copy16(bptr[p] + kb, (char*)Bs + p * 4096 + t * 16);
        __syncthreads();
        #pragma unroll
        for (int ks = 0; ks < 2; ++ks) {
            bf16x8 af[4], bfr[4];
            #pragma unroll
            for (int i = 0; i < 4; ++i)
                af[i] = *(const bf16x8*)&As[(wm + i * 16 + l15) * BK + ks * 32 + qk];
            #pragma unroll
            for (int j = 0; j < 4; ++j)
                bfr[j] = *(const bf16x8*)&Bs[(wn + j * 16 + l15) * BK + ks * 32 + qk];
            #pragma unroll
            for (int i = 0; i < 4; ++i)
                #pragma unroll
                for (int j = 0; j < 4; ++j)
                    acc[i][j] = __builtin_amdgcn_mfma_f32_16x16x32_bf16(af[i], bfr[j], acc[i][j], 0, 0, 0);
        }
        __syncthreads();
    }

    int q4 = (lane >> 4) * 4;
    #pragma unroll
    for (int i = 0; i < 4; ++i) {
        #pragma unroll
        for (int r = 0; r < 4; ++r) {
            int m = tm * BM + wm + i * 16 + q4 + r;
            if (m < count) {
                size_t rowbase = (size_t)(off + m) * NH;
                #pragma unroll
                for (int j = 0; j < 4; ++j) {
                    int col = tn * BN + wn + j * 16 + l15;
                    float v = acc[i][j][r] + hb[e * NH + col];
                    v = v / (1.0f + __expf(-v));           // silu
                    hbuf[rowbase + col] = f2bf(v);
                }
            }
        }
    }
}

// GEMM2: eo[slot][col] = hbuf[slot] . wo[e][col] + bias, fp32 out
__global__ __launch_bounds__(256) void gemm2_kernel(
    const unsigned short* __restrict__ hbuf,  // [2N][H] bf16
    const unsigned short* __restrict__ wo,    // [E][O][H] bf16
    const float* __restrict__ ob,             // [E][O]
    const int* __restrict__ counts, const int* __restrict__ offsets,
    float* __restrict__ eo)                   // [2N][O] fp32
{
    int e = blockIdx.z;
    int count = counts[e];
    int tm = blockIdx.y, tn = blockIdx.x;
    if (tm * BM >= count) return;
    int off = offsets[e];

    __shared__ alignas(16) short As[BM * BK];
    __shared__ alignas(16) short Bs[BN * BK];

    int t = threadIdx.x;
    int c = t & 7, rl = t >> 3;
    const unsigned short* aptr[4];
    const unsigned short* bptr[4];
    #pragma unroll
    for (int p = 0; p < 4; ++p) {
        int mrow = tm * BM + p * 32 + rl;
        int mc = mrow < count ? mrow : count - 1;
        aptr[p] = hbuf + (size_t)(off + mc) * NH;
        int nrow = tn * BN + p * 32 + rl;
        bptr[p] = wo + ((size_t)e * NO + nrow) * NH;
    }

    int lane = t & 63, wvi = t >> 6;
    int wm = (wvi & 1) * 64, wn = (wvi >> 1) * 64;
    int l15 = lane & 15, qk = (lane >> 4) * 8;

    f32x4 acc[4][4];
    #pragma unroll
    for (int i = 0; i < 4; ++i)
        #pragma unroll
        for (int j = 0; j < 4; ++j) acc[i][j] = (f32x4){0.f, 0.f, 0.f, 0.f};

    for (int kt = 0; kt < NH / BK; ++kt) {
        int kb = kt * BK + c * 8;
        #pragma unroll
        for (int p = 0; p < 4; ++p)
            async_copy16(aptr[p] + kb, (char*)As + p * 4096 + t * 16);
        #pragma unroll
        for (int p = 0; p < 4; ++p)
            async_copy16(bptr[p] + kb, (char*)Bs + p * 4096 + t * 16);
        __syncthreads();
        #pragma unroll
        for (int ks = 0; ks < 2; ++ks) {
            bf16x8 af[4], bfr[4];
            #pragma unroll
            for (int i = 0; i < 4; ++i)
                af[i] = *(const bf16x8*)&As[(wm + i * 16 + l15) * BK + ks * 32 + qk];
            #pragma unroll
            for (int j = 0; j < 4; ++j)
                bfr[j] = *(const bf16x8*)&Bs[(wn + j * 16 + l15) * BK + ks * 32 + qk];
            #pragma unroll
            for (int i = 0; i < 4; ++i)
                #pragma unroll
                for (int j = 0; j < 4; ++j)
                    acc[i][j] = __builtin_amdgcn_mfma_f32_16x16x32_bf16(af[i], bfr[j], acc[i][j], 0, 0, 0);
        }
        __syncthreads();
    }

    int q4 = (lane >> 4) * 4;
    #pragma unroll
    for (int i = 0; i < 4; ++i) {
        #pragma unroll
        for (int r = 0; r < 4; ++r) {
            int m = tm * BM + wm + i * 16 + q4 + r;
            if (m < count) {
                size_t rowbase = (size_t)(off + m) * NO;
                #pragma unroll
                for (int j = 0; j < 4; ++j) {
                    int col = tn * BN + wn + j * 16 + l15;
                    eo[rowbase + col] = acc[i][j][r] + ob[e * NO + col];
                }
            }
        }
    }
}

// Residual GEMM: y[n][o] = x_bf[n] . woutT[o]
__global__ __launch_bounds__(256) void gemm_res_kernel(
    const unsigned short* __restrict__ xb,   // [N][D] bf16
    const unsigned short* __restrict__ wt,   // [O][D] bf16
    float* __restrict__ y)                   // [N][O] fp32
{
    int tm = blockIdx.y, tn = blockIdx.x;
    __shared__ alignas(16) short As[BM * BK];
    __shared__ alignas(16) short Bs[BN * BK];

    int t = threadIdx.x;
    int c = t & 7, rl = t >> 3;
    const unsigned short* aptr[4];
    const unsigned short* bptr[4];
    #pragma unroll
    for (int p = 0; p < 4; ++p) {
        aptr[p] = xb + (size_t)(tm * BM + p * 32 + rl) * DIM;
        bptr[p] = wt + (size_t)(tn * BN + p * 32 + rl) * DIM;
    }

    int lane = t & 63, wvi = t >> 6;
    int wm = (wvi & 1) * 64, wn = (wvi >> 1) * 64;
    int l15 = lane & 15, qk = (lane >> 4) * 8;

    f32x4 acc[4][4];
    #pragma unroll
    for (int i = 0; i < 4; ++i)
        #pragma unroll
        for (int j = 0; j < 4; ++j) acc[i][j] = (f32x4){0.f, 0.f, 0.f, 0.f};

    for (int kt = 0; kt < DIM / BK; ++kt) {
        int kb = kt * BK + c * 8;
        #pragma unroll
        for (int p = 0; p < 4; ++p)
            async_copy16(aptr[p] + kb, (char*)As + p * 4096 + t * 16);
        #pragma unroll
        for (int p = 0; p < 4; ++p)
            async_copy16(bptr[p] + kb, (char*)Bs + p * 4096 + t * 16);
        __syncthreads();
        #pragma unroll
        for (int ks = 0; ks < 2; ++ks) {
            bf16x8 af[4], bfr[4];
            #pragma unroll
            for (int i = 0; i < 4; ++i)
                af[i] = *(const bf16x8*)&As[(wm + i * 16 + l15) * BK + ks * 32 + qk];
            #pragma unroll
            for (int j = 0; j < 4; ++j)
                bfr[j] = *(const bf16x8*)&Bs[(wn + j * 16 + l15) * BK + ks * 32 + qk];
            #pragma unroll
            for (int i = 0; i < 4; ++i)
                #pragma unroll
                for (int j = 0; j < 4; ++j)
                    acc[i][j] = __builtin_amdgcn_mfma_f32_16x16x32_bf16(af[i], bfr[j], acc[i][j], 0, 0, 0);
        }
        __syncthreads();
    }

    int q4 = (lane >> 4) * 4;
    #pragma unroll
    for (int i = 0; i < 4; ++i) {
        #pragma unroll
        for (int r = 0; r < 4; ++r) {
            int row = tm * BM + wm + i * 16 + q4 + r;
            #pragma unroll
            for (int j = 0; j < 4; ++j) {
                int col = tn * BN + wn + j * 16 + l15;
                y[(size_t)row * NO + col] = acc[i][j][r];
            }
        }
    }
}

// ---------------- gated combine: y += g0*eo[p0] + g1*eo[p1] ----------------
__global__ __launch_bounds__(256) void combine_kernel(
    float* __restrict__ y, const float* __restrict__ eo,
    const int* __restrict__ pair_slot, const float* __restrict__ tok_g)
{
    int n = blockIdx.x, t = threadIdx.x;
    int s0 = pair_slot[2 * n], s1 = pair_slot[2 * n + 1];
    float g0 = tok_g[2 * n], g1 = tok_g[2 * n + 1];
    float4 a = ((const float4*)(eo + (size_t)s0 * NO))[t];
    float4 b = ((const float4*)(eo + (size_t)s1 * NO))[t];
    float4* yp = (float4*)(y + (size_t)n * NO) + t;
    float4 v = *yp;
    v.x += g0 * a.x + g1 * b.x;
    v.y += g0 * a.y + g1 * b.y;
    v.z += g0 * a.z + g1 * b.z;
    v.w += g0 * a.w + g1 * b.w;
    *yp = v;
}

extern "C" void kernel_launch(void* const* d_in, const int* in_sizes, int n_in,
                              void* d_out, int out_size, void* d_ws, size_t ws_size,
                              hipStream_t stream) {
    const float* x    = (const float*)d_in[0];
    const float* nw   = (const float*)d_in[6];
    const float* nb   = (const float*)d_in[7];
    const float* eps  = (const float*)d_in[8];
    const float* wg   = (const float*)d_in[9];
    const float* whw  = (const float*)d_in[10];
    const float* whb  = (const float*)d_in[11];
    const float* wow  = (const float*)d_in[12];
    const float* wob  = (const float*)d_in[13];
    const float* wout = (const float*)d_in[14];

    char* ws = (char*)d_ws;
    // workspace layout (bytes)
    unsigned short* xn_bf = (unsigned short*)(ws + 0);          //  8,388,608
    unsigned short* x_bf  = (unsigned short*)(ws + 8388608);    //  8,388,608
    unsigned short* wh_bf = (unsigned short*)(ws + 16777216);   // 33,554,432
    float*          eo    = (float*)(ws + 16777216);            // alias: used after gemm1 done
    unsigned short* wo_bf = (unsigned short*)(ws + 50331648);   // 33,554,432
    unsigned short* wt_bf = (unsigned short*)(ws + 83886080);   //  2,097,152
    unsigned short* hbuf  = (unsigned short*)(ws + 85983232);   // 33,554,432
    char* meta = ws + 119537664;
    int*   counts     = (int*)(meta + 0);
    float* importance = (float*)(meta + 32);
    int*   offsets    = (int*)(meta + 64);
    int*   cursor     = (int*)(meta + 96);
    int*   tok_e      = (int*)(meta + 128);
    float* tok_g      = (float*)(meta + 128 + 32768);
    int*   rowsbuf    = (int*)(meta + 128 + 65536);
    int*   pair_slot  = (int*)(meta + 128 + 98304);

    float* y = (float*)d_out;
    float* out_tail = y + (size_t)N_TOK * NO;   // loss, then gate_fraction[8]

    zero_meta_kernel<<<1, 64, 0, stream>>>(counts, importance);
    ln_gate_kernel<<<N_TOK, 256, 0, stream>>>(x, nw, nb, eps, wg, xn_bf, x_bf,
                                              tok_e, tok_g, counts, importance);
    {
        int n4 = NE * NH * DIM / 4;   // 4,194,304 (same for wo: E*O*H)
        cvt_bf16_kernel<<<n4 / 256, 256, 0, stream>>>(whw, wh_bf, n4);
        cvt_bf16_kernel<<<n4 / 256, 256, 0, stream>>>(wow, wo_bf, n4);
    }
    transpose_cvt_kernel<<<dim3(NO / 32, DIM / 32), dim3(32, 32), 0, stream>>>(wout, wt_bf);
    finalize_kernel<<<1, 1, 0, stream>>>(counts, importance, offsets, cursor, out_tail);
    scatter_kernel<<<N_TOK / 256, 256, 0, stream>>>(tok_e, cursor, rowsbuf, pair_slot);
    gemm1_kernel<<<dim3(NH / BN, N_TOK / BM, NE), 256, 0, stream>>>(
        xn_bf, wh_bf, whb, rowsbuf, counts, offsets, hbuf);
    gemm2_kernel<<<dim3(NO / BN, N_TOK / BM, NE), 256, 0, stream>>>(
        hbuf, wo_bf, wob, counts, offsets, eo);
    gemm_res_kernel<<<dim3(NO / BN, N_TOK / BM), 256, 0, stream>>>(x_bf, wt_bf, y);
    combine_kernel<<<N_TOK, 256, 0, stream>>>(y, eo, pair_slot, tok_g);
}

// Round 2
// 447.641 us; speedup vs baseline: 1.4617x; 1.4617x over previous
//
#include <hip/hip_runtime.h>
#include <hip/hip_bf16.h>
#include <stdint.h>

// Problem constants (from reference setup_inputs)
#define N_TOK 4096
#define DIM   1024
#define NE    8
#define NH    2048
#define NO    1024

typedef __attribute__((ext_vector_type(8))) short bf16x8;
typedef __attribute__((ext_vector_type(4))) float f32x4;

__device__ inline unsigned short f2bf(float f) {
    unsigned u = __float_as_uint(f);
    u += 0x7fffu + ((u >> 16) & 1u);   // round-to-nearest-even
    return (unsigned short)(u >> 16);
}

__device__ inline void async_copy16(const void* g, void* l) {
    __builtin_amdgcn_global_load_lds(
        (const __attribute__((address_space(1))) void*)g,
        (__attribute__((address_space(3))) void*)l, 16, 0, 0);
}

// ---------------- fused layernorm + gating (NO atomics) ----------------
// one block (256 thr) per token row
__global__ __launch_bounds__(256) void ln_gate_kernel(
    const float* __restrict__ x, const float* __restrict__ nw,
    const float* __restrict__ nb, const float* __restrict__ eps_p,
    const float* __restrict__ wg,
    unsigned short* __restrict__ xn_bf, unsigned short* __restrict__ x_bf,
    int* __restrict__ tok_e, float* __restrict__ tok_g)
{
    int n = blockIdx.x;
    int t = threadIdx.x;
    int lane = t & 63, wv = t >> 6;

    const float4 xv = ((const float4*)(x + (size_t)n * DIM))[t];
    float s  = xv.x + xv.y + xv.z + xv.w;
    float s2 = xv.x*xv.x + xv.y*xv.y + xv.z*xv.z + xv.w*xv.w;
    #pragma unroll
    for (int o = 32; o > 0; o >>= 1) {
        s  += __shfl_down(s, o);
        s2 += __shfl_down(s2, o);
    }
    __shared__ float rs[4], rs2[4];
    __shared__ float gred[4][NE];
    if (lane == 0) { rs[wv] = s; rs2[wv] = s2; }
    __syncthreads();
    float S  = rs[0] + rs[1] + rs[2] + rs[3];
    float S2 = rs2[0] + rs2[1] + rs2[2] + rs2[3];
    const float inv = 1.0f / (float)DIM;
    float mu = S * inv;
    float var = fmaxf(S2 * inv - mu * mu, 0.0f);   // biased, like F.layer_norm
    float rstd = rsqrtf(var + eps_p[0]);

    float4 w4 = ((const float4*)nw)[t];
    float4 b4 = ((const float4*)nb)[t];
    float xn0 = (xv.x - mu) * rstd * w4.x + b4.x;
    float xn1 = (xv.y - mu) * rstd * w4.y + b4.y;
    float xn2 = (xv.z - mu) * rstd * w4.z + b4.z;
    float xn3 = (xv.w - mu) * rstd * w4.w + b4.w;

    ushort4 pn; pn.x = f2bf(xn0); pn.y = f2bf(xn1); pn.z = f2bf(xn2); pn.w = f2bf(xn3);
    ((ushort4*)(xn_bf + (size_t)n * DIM))[t] = pn;
    ushort4 px; px.x = f2bf(xv.x); px.y = f2bf(xv.y); px.z = f2bf(xv.z); px.w = f2bf(xv.w);
    ((ushort4*)(x_bf + (size_t)n * DIM))[t] = px;

    // gating logits: x_norm (fp32) @ w_gate [D][E]
    float acc[NE];
    #pragma unroll
    for (int e = 0; e < NE; ++e) acc[e] = 0.0f;
    float xns[4] = {xn0, xn1, xn2, xn3};
    const float4* wgp = (const float4*)(wg + (size_t)(4 * t) * NE);
    #pragma unroll
    for (int j = 0; j < 4; ++j) {
        float4 w0 = wgp[2 * j], w1 = wgp[2 * j + 1];
        float xj = xns[j];
        acc[0] += xj * w0.x; acc[1] += xj * w0.y; acc[2] += xj * w0.z; acc[3] += xj * w0.w;
        acc[4] += xj * w1.x; acc[5] += xj * w1.y; acc[6] += xj * w1.z; acc[7] += xj * w1.w;
    }
    #pragma unroll
    for (int o = 32; o > 0; o >>= 1) {
        #pragma unroll
        for (int e = 0; e < NE; ++e) acc[e] += __shfl_down(acc[e], o);
    }
    if (lane == 0) {
        #pragma unroll
        for (int e = 0; e < NE; ++e) gred[wv][e] = acc[e];
    }
    __syncthreads();
    if (t == 0) {
        float lg[NE];
        float nrm2 = 0.0f;
        #pragma unroll
        for (int e = 0; e < NE; ++e) {
            lg[e] = gred[0][e] + gred[1][e] + gred[2][e] + gred[3][e];
            nrm2 += lg[e] * lg[e];
        }
        float den = fmaxf(sqrtf(nrm2), 1e-12f);
        float linv = 1.0f / den;
        #pragma unroll
        for (int e = 0; e < NE; ++e) lg[e] *= linv;
        float mx = lg[0];
        #pragma unroll
        for (int e = 1; e < NE; ++e) mx = fmaxf(mx, lg[e]);
        float p[NE], ps = 0.0f;
        #pragma unroll
        for (int e = 0; e < NE; ++e) { p[e] = expf(lg[e] - mx); ps += p[e]; }
        float pinv = 1.0f / ps;
        #pragma unroll
        for (int e = 0; e < NE; ++e) p[e] *= pinv;
        // top-2, lowest-index wins ties (jax.lax.top_k semantics)
        int i0 = 0; float b0 = lg[0];
        #pragma unroll
        for (int e = 1; e < NE; ++e) if (lg[e] > b0) { b0 = lg[e]; i0 = e; }
        int i1 = -1; float b1 = -3.0e38f;
        #pragma unroll
        for (int e = 0; e < NE; ++e) if (e != i0 && lg[e] > b1) { b1 = lg[e]; i1 = e; }
        tok_e[2 * n] = i0; tok_e[2 * n + 1] = i1;
        tok_g[2 * n] = p[i0]; tok_g[2 * n + 1] = p[i1];
    }
}

// ---------------- fp32 -> bf16 bulk convert ----------------
__global__ void cvt_bf16_kernel(const float* __restrict__ src,
                                unsigned short* __restrict__ dst, int n4) {
    int i = blockIdx.x * blockDim.x + threadIdx.x;
    if (i < n4) {
        float4 v = ((const float4*)src)[i];
        ushort4 o; o.x = f2bf(v.x); o.y = f2bf(v.y); o.z = f2bf(v.z); o.w = f2bf(v.w);
        ((ushort4*)dst)[i] = o;
    }
}

// ---------------- output_weight [D][O] -> bf16 [O][D] ----------------
__global__ void transpose_cvt_kernel(const float* __restrict__ w,
                                     unsigned short* __restrict__ wt) {
    __shared__ float tile[32][33];
    int tx = threadIdx.x, ty = threadIdx.y;
    int o0 = blockIdx.x * 32, d0 = blockIdx.y * 32;
    tile[ty][tx] = w[(size_t)(d0 + ty) * NO + o0 + tx];
    __syncthreads();
    wt[(size_t)(o0 + ty) * DIM + d0 + tx] = f2bf(tile[tx][ty]);
}

// ---------------- count + finalize: histogram reduce, offsets, loss ----------------
__device__ inline float cv_sq(const float* v) {
    float m = 0.0f;
    for (int e = 0; e < NE; ++e) m += v[e];
    m *= (1.0f / NE);
    float s = 0.0f;
    for (int e = 0; e < NE; ++e) { float d = v[e] - m; s += d * d; }
    s *= (1.0f / (NE - 1));          // ddof=1
    return s / (m * m + 1e-6f);
}

// single block, 1024 threads; replaces zero_meta + atomics + finalize
__global__ __launch_bounds__(1024) void count_finalize_kernel(
    const int* __restrict__ tok_e, const float* __restrict__ tok_g,
    int* __restrict__ counts, int* __restrict__ offsets,
    int* __restrict__ cursor_pad, float* __restrict__ out_tail)
{
    int t = threadIdx.x;
    int lane = t & 63, wv = t >> 6;   // 16 waves
    int lc[NE]; float li[NE];
    #pragma unroll
    for (int e = 0; e < NE; ++e) { lc[e] = 0; li[e] = 0.0f; }
    // 8192 entries, 8 per thread (two int4/float4 loads)
    const int4* ep = (const int4*)(tok_e) + 2 * t;
    const float4* gp = (const float4*)(tok_g) + 2 * t;
    #pragma unroll
    for (int q = 0; q < 2; ++q) {
        int4 e4 = ep[q]; float4 g4 = gp[q];
        lc[e4.x]++; li[e4.x] += g4.x;
        lc[e4.y]++; li[e4.y] += g4.y;
        lc[e4.z]++; li[e4.z] += g4.z;
        lc[e4.w]++; li[e4.w] += g4.w;
    }
    #pragma unroll
    for (int o = 32; o > 0; o >>= 1) {
        #pragma unroll
        for (int e = 0; e < NE; ++e) {
            lc[e] += __shfl_down(lc[e], o);
            li[e] += __shfl_down(li[e], o);
        }
    }
    __shared__ int   sc[16][NE];
    __shared__ float sf[16][NE];
    if (lane == 0) {
        #pragma unroll
        for (int e = 0; e < NE; ++e) { sc[wv][e] = lc[e]; sf[wv][e] = li[e]; }
    }
    __syncthreads();
    if (t == 0) {
        float lif[NE], lcf[NE];
        int off = 0;
        for (int e = 0; e < NE; ++e) {
            int c = 0; float im = 0.0f;
            for (int w = 0; w < 16; ++w) { c += sc[w][e]; im += sf[w][e]; }
            counts[e] = c;
            offsets[e] = off;
            cursor_pad[e * 32] = off;   // one 128B line per expert
            off += c;
            lcf[e] = (float)c; lif[e] = im;
        }
        float tot = (float)off;
        out_tail[0] = 0.01f * (cv_sq(lif) + cv_sq(lcf));     // loss
        for (int e = 0; e < NE; ++e) out_tail[1 + e] = lcf[e] / tot;  // gate_fraction
    }
}

// ---------------- hierarchical scatter (few global atomics) ----------------
// 8 blocks x 256 threads; each block handles 512 tokens (1024 entries)
__global__ __launch_bounds__(256) void scatter_kernel(
    const int* __restrict__ tok_e, int* __restrict__ cursor_pad,
    int* __restrict__ rowsbuf, int* __restrict__ pair_slot)
{
    __shared__ int lhist[NE];
    __shared__ int lbase[NE];
    int t = threadIdx.x;
    int tok0 = blockIdx.x * 512 + 2 * t;     // 2 tokens per thread -> int4
    if (t < NE) lhist[t] = 0;
    __syncthreads();
    int4 e4 = *(const int4*)(tok_e + 2 * tok0);
    int r0 = atomicAdd(&lhist[e4.x], 1);
    int r1 = atomicAdd(&lhist[e4.y], 1);
    int r2 = atomicAdd(&lhist[e4.z], 1);
    int r3 = atomicAdd(&lhist[e4.w], 1);
    __syncthreads();
    if (t < NE) lbase[t] = atomicAdd(&cursor_pad[t * 32], lhist[t]);
    __syncthreads();
    int s0 = lbase[e4.x] + r0;
    int s1 = lbase[e4.y] + r1;
    int s2 = lbase[e4.z] + r2;
    int s3 = lbase[e4.w] + r3;
    rowsbuf[s0] = tok0;     rowsbuf[s1] = tok0;
    rowsbuf[s2] = tok0 + 1; rowsbuf[s3] = tok0 + 1;
    *(int4*)(pair_slot + 2 * tok0) = (int4){s0, s1, s2, s3};
}

// ---------------- GEMM common tile params ----------------
#define BM 128
#define BN 128
#define BK 64

// GEMM1: h[slot][col] = silu( xn[token] . wh[e][col] + bias ), bf16 out
__global__ __launch_bounds__(256) void gemm1_kernel(
    const unsigned short* __restrict__ xn,   // [N][D] bf16
    const unsigned short* __restrict__ wh,   // [E][H][D] bf16
    const float* __restrict__ hb,            // [E][H]
    const int* __restrict__ rowsbuf,
    const int* __restrict__ counts, const int* __restrict__ offsets,
    unsigned short* __restrict__ hbuf)       // [2N][H] bf16
{
    int e = blockIdx.z;
    int count = counts[e];
    int tm = blockIdx.y, tn = blockIdx.x;
    if (tm * BM >= count) return;
    int off = offsets[e];

    __shared__ alignas(16) short As[BM * BK];
    __shared__ alignas(16) short Bs[BN * BK];

    int t = threadIdx.x;
    int c = t & 7, rl = t >> 3;
    const unsigned short* aptr[4];
    const unsigned short* bptr[4];
    #pragma unroll
    for (int p = 0; p < 4; ++p) {
        int mrow = tm * BM + p * 32 + rl;
        int mc = mrow < count ? mrow : count - 1;
        int token = rowsbuf[off + mc];
        aptr[p] = xn + (size_t)token * DIM;
        int nrow = tn * BN + p * 32 + rl;
        bptr[p] = wh + ((size_t)e * NH + nrow) * DIM;
    }

    int lane = t & 63, wvi = t >> 6;
    int wm = (wvi & 1) * 64, wn = (wvi >> 1) * 64;
    int l15 = lane & 15, qk = (lane >> 4) * 8;

    f32x4 acc[4][4];
    #pragma unroll
    for (int i = 0; i < 4; ++i)
        #pragma unroll
        for (int j = 0; j < 4; ++j) acc[i][j] = (f32x4){0.f, 0.f, 0.f, 0.f};

    for (int kt = 0; kt < DIM / BK; ++kt) {
        int kb = kt * BK + c * 8;
        #pragma unroll
        for (int p = 0; p < 4; ++p)
            async_copy16(aptr[p] + kb, (char*)As + p * 4096 + t * 16);
        #pragma unroll
        for (int p = 0; p < 4; ++p)
            async_copy16(bptr[p] + kb, (char*)Bs + p * 4096 + t * 16);
        __syncthreads();
        #pragma unroll
        for (int ks = 0; ks < 2; ++ks) {
            bf16x8 af[4], bfr[4];
            #pragma unroll
            for (int i = 0; i < 4; ++i)
                af[i] = *(const bf16x8*)&As[(wm + i * 16 + l15) * BK + ks * 32 + qk];
            #pragma unroll
            for (int j = 0; j < 4; ++j)
                bfr[j] = *(const bf16x8*)&Bs[(wn + j * 16 + l15) * BK + ks * 32 + qk];
            #pragma unroll
            for (int i = 0; i < 4; ++i)
                #pragma unroll
                for (int j = 0; j < 4; ++j)
                    acc[i][j] = __builtin_amdgcn_mfma_f32_16x16x32_bf16(af[i], bfr[j], acc[i][j], 0, 0, 0);
        }
        __syncthreads();
    }

    int q4 = (lane >> 4) * 4;
    #pragma unroll
    for (int i = 0; i < 4; ++i) {
        #pragma unroll
        for (int r = 0; r < 4; ++r) {
            int m = tm * BM + wm + i * 16 + q4 + r;
            if (m < count) {
                size_t rowbase = (size_t)(off + m) * NH;
                #pragma unroll
                for (int j = 0; j < 4; ++j) {
                    int col = tn * BN + wn + j * 16 + l15;
                    float v = acc[i][j][r] + hb[e * NH + col];
                    v = v / (1.0f + __expf(-v));           // silu
                    hbuf[rowbase + col] = f2bf(v);
                }
            }
        }
    }
}

// GEMM2: eo[slot][col] = hbuf[slot] . wo[e][col] + bias, fp32 out
__global__ __launch_bounds__(256) void gemm2_kernel(
    const unsigned short* __restrict__ hbuf,  // [2N][H] bf16
    const unsigned short* __restrict__ wo,    // [E][O][H] bf16
    const float* __restrict__ ob,             // [E][O]
    const int* __restrict__ counts, const int* __restrict__ offsets,
    float* __restrict__ eo)                   // [2N][O] fp32
{
    int e = blockIdx.z;
    int count = counts[e];
    int tm = blockIdx.y, tn = blockIdx.x;
    if (tm * BM >= count) return;
    int off = offsets[e];

    __shared__ alignas(16) short As[BM * BK];
    __shared__ alignas(16) short Bs[BN * BK];

    int t = threadIdx.x;
    int c = t & 7, rl = t >> 3;
    const unsigned short* aptr[4];
    const unsigned short* bptr[4];
    #pragma unroll
    for (int p = 0; p < 4; ++p) {
        int mrow = tm * BM + p * 32 + rl;
        int mc = mrow < count ? mrow : count - 1;
        aptr[p] = hbuf + (size_t)(off + mc) * NH;
        int nrow = tn * BN + p * 32 + rl;
        bptr[p] = wo + ((size_t)e * NO + nrow) * NH;
    }

    int lane = t & 63, wvi = t >> 6;
    int wm = (wvi & 1) * 64, wn = (wvi >> 1) * 64;
    int l15 = lane & 15, qk = (lane >> 4) * 8;

    f32x4 acc[4][4];
    #pragma unroll
    for (int i = 0; i < 4; ++i)
        #pragma unroll
        for (int j = 0; j < 4; ++j) acc[i][j] = (f32x4){0.f, 0.f, 0.f, 0.f};

    for (int kt = 0; kt < NH / BK; ++kt) {
        int kb = kt * BK + c * 8;
        #pragma unroll
        for (int p = 0; p < 4; ++p)
            async_copy16(aptr[p] + kb, (char*)As + p * 4096 + t * 16);
        #pragma unroll
        for (int p = 0; p < 4; ++p)
            async_copy16(bptr[p] + kb, (char*)Bs + p * 4096 + t * 16);
        __syncthreads();
        #pragma unroll
        for (int ks = 0; ks < 2; ++ks) {
            bf16x8 af[4], bfr[4];
            #pragma unroll
            for (int i = 0; i < 4; ++i)
                af[i] = *(const bf16x8*)&As[(wm + i * 16 + l15) * BK + ks * 32 + qk];
            #pragma unroll
            for (int j = 0; j < 4; ++j)
                bfr[j] = *(const bf16x8*)&Bs[(wn + j * 16 + l15) * BK + ks * 32 + qk];
            #pragma unroll
            for (int i = 0; i < 4; ++i)
                #pragma unroll
                for (int j = 0; j < 4; ++j)
                    acc[i][j] = __builtin_amdgcn_mfma_f32_16x16x32_bf16(af[i], bfr[j], acc[i][j], 0, 0, 0);
        }
        __syncthreads();
    }

    int q4 = (lane >> 4) * 4;
    #pragma unroll
    for (int i = 0; i < 4; ++i) {
        #pragma unroll
        for (int r = 0; r < 4; ++r) {
            int m = tm * BM + wm + i * 16 + q4 + r;
            if (m < count) {
                size_t rowbase = (size_t)(off + m) * NO;
                #pragma unroll
                for (int j = 0; j < 4; ++j) {
                    int col = tn * BN + wn + j * 16 + l15;
                    eo[rowbase + col] = acc[i][j][r] + ob[e * NO + col];
                }
            }
        }
    }
}

// Residual GEMM: y[n][o] = x_bf[n] . woutT[o]
__global__ __launch_bounds__(256) void gemm_res_kernel(
    const unsigned short* __restrict__ xb,   // [N][D] bf16
    const unsigned short* __restrict__ wt,   // [O][D] bf16
    float* __restrict__ y)                   // [N][O] fp32
{
    int tm = blockIdx.y, tn = blockIdx.x;
    __shared__ alignas(16) short As[BM * BK];
    __shared__ alignas(16) short Bs[BN * BK];

    int t = threadIdx.x;
    int c = t & 7, rl = t >> 3;
    const unsigned short* aptr[4];
    const unsigned short* bptr[4];
    #pragma unroll
    for (int p = 0; p < 4; ++p) {
        aptr[p] = xb + (size_t)(tm * BM + p * 32 + rl) * DIM;
        bptr[p] = wt + (size_t)(tn * BN + p * 32 + rl) * DIM;
    }

    int lane = t & 63, wvi = t >> 6;
    int wm = (wvi & 1) * 64, wn = (wvi >> 1) * 64;
    int l15 = lane & 15, qk = (lane >> 4) * 8;

    f32x4 acc[4][4];
    #pragma unroll
    for (int i = 0; i < 4; ++i)
        #pragma unroll
        for (int j = 0; j < 4; ++j) acc[i][j] = (f32x4){0.f, 0.f, 0.f, 0.f};

    for (int kt = 0; kt < DIM / BK; ++kt) {
        int kb = kt * BK + c * 8;
        #pragma unroll
        for (int p = 0; p < 4; ++p)
            async_copy16(aptr[p] + kb, (char*)As + p * 4096 + t * 16);
        #pragma unroll
        for (int p = 0; p < 4; ++p)
            async_copy16(bptr[p] + kb, (char*)Bs + p * 4096 + t * 16);
        __syncthreads();
        #pragma unroll
        for (int ks = 0; ks < 2; ++ks) {
            bf16x8 af[4], bfr[4];
            #pragma unroll
            for (int i = 0; i < 4; ++i)
                af[i] = *(const bf16x8*)&As[(wm + i * 16 + l15) * BK + ks * 32 + qk];
            #pragma unroll
            for (int j = 0; j < 4; ++j)
                bfr[j] = *(const bf16x8*)&Bs[(wn + j * 16 + l15) * BK + ks * 32 + qk];
            #pragma unroll
            for (int i = 0; i < 4; ++i)
                #pragma unroll
                for (int j = 0; j < 4; ++j)
                    acc[i][j] = __builtin_amdgcn_mfma_f32_16x16x32_bf16(af[i], bfr[j], acc[i][j], 0, 0, 0);
        }
        __syncthreads();
    }

    int q4 = (lane >> 4) * 4;
    #pragma unroll
    for (int i = 0; i < 4; ++i) {
        #pragma unroll
        for (int r = 0; r < 4; ++r) {
            int row = tm * BM + wm + i * 16 + q4 + r;
            #pragma unroll
            for (int j = 0; j < 4; ++j) {
                int col = tn * BN + wn + j * 16 + l15;
                y[(size_t)row * NO + col] = acc[i][j][r];
            }
        }
    }
}

// ---------------- gated combine: y += g0*eo[p0] + g1*eo[p1] ----------------
__global__ __launch_bounds__(256) void combine_kernel(
    float* __restrict__ y, const float* __restrict__ eo,
    const int* __restrict__ pair_slot, const float* __restrict__ tok_g)
{
    int n = blockIdx.x, t = threadIdx.x;
    int s0 = pair_slot[2 * n], s1 = pair_slot[2 * n + 1];
    float g0 = tok_g[2 * n], g1 = tok_g[2 * n + 1];
    float4 a = ((const float4*)(eo + (size_t)s0 * NO))[t];
    float4 b = ((const float4*)(eo + (size_t)s1 * NO))[t];
    float4* yp = (float4*)(y + (size_t)n * NO) + t;
    float4 v = *yp;
    v.x += g0 * a.x + g1 * b.x;
    v.y += g0 * a.y + g1 * b.y;
    v.z += g0 * a.z + g1 * b.z;
    v.w += g0 * a.w + g1 * b.w;
    *yp = v;
}

extern "C" void kernel_launch(void* const* d_in, const int* in_sizes, int n_in,
                              void* d_out, int out_size, void* d_ws, size_t ws_size,
                              hipStream_t stream) {
    const float* x    = (const float*)d_in[0];
    const float* nw   = (const float*)d_in[6];
    const float* nb   = (const float*)d_in[7];
    const float* eps  = (const float*)d_in[8];
    const float* wg   = (const float*)d_in[9];
    const float* whw  = (const float*)d_in[10];
    const float* whb  = (const float*)d_in[11];
    const float* wow  = (const float*)d_in[12];
    const float* wob  = (const float*)d_in[13];
    const float* wout = (const float*)d_in[14];

    char* ws = (char*)d_ws;
    // workspace layout (bytes)
    unsigned short* xn_bf = (unsigned short*)(ws + 0);          //  8,388,608
    unsigned short* x_bf  = (unsigned short*)(ws + 8388608);    //  8,388,608
    unsigned short* wh_bf = (unsigned short*)(ws + 16777216);   // 33,554,432
    float*          eo    = (float*)(ws + 16777216);            // alias: used after gemm1 done
    unsigned short* wo_bf = (unsigned short*)(ws + 50331648);   // 33,554,432
    unsigned short* wt_bf = (unsigned short*)(ws + 83886080);   //  2,097,152
    unsigned short* hbuf  = (unsigned short*)(ws + 85983232);   // 33,554,432
    char* meta = ws + 119537664;
    int*   counts     = (int*)(meta + 0);
    int*   offsets    = (int*)(meta + 128);
    int*   cursor_pad = (int*)(meta + 256);     // 8 experts x 128B stride
    int*   tok_e      = (int*)(meta + 2048);
    float* tok_g      = (float*)(meta + 2048 + 32768);
    int*   rowsbuf    = (int*)(meta + 2048 + 65536);
    int*   pair_slot  = (int*)(meta + 2048 + 98304);

    float* y = (float*)d_out;
    float* out_tail = y + (size_t)N_TOK * NO;   // loss, then gate_fraction[8]

    ln_gate_kernel<<<N_TOK, 256, 0, stream>>>(x, nw, nb, eps, wg, xn_bf, x_bf,
                                              tok_e, tok_g);
    {
        int n4 = NE * NH * DIM / 4;   // 4,194,304 (same for wo: E*O*H)
        cvt_bf16_kernel<<<n4 / 256, 256, 0, stream>>>(whw, wh_bf, n4);
        cvt_bf16_kernel<<<n4 / 256, 256, 0, stream>>>(wow, wo_bf, n4);
    }
    transpose_cvt_kernel<<<dim3(NO / 32, DIM / 32), dim3(32, 32), 0, stream>>>(wout, wt_bf);
    count_finalize_kernel<<<1, 1024, 0, stream>>>(tok_e, tok_g, counts, offsets,
                                                  cursor_pad, out_tail);
    scatter_kernel<<<N_TOK / 512, 256, 0, stream>>>(tok_e, cursor_pad, rowsbuf, pair_slot);
    gemm1_kernel<<<dim3(NH / BN, N_TOK / BM, NE), 256, 0, stream>>>(
        xn_bf, wh_bf, whb, rowsbuf, counts, offsets, hbuf);
    gemm2_kernel<<<dim3(NO / BN, N_TOK / BM, NE), 256, 0, stream>>>(
        hbuf, wo_bf, wob, counts, offsets, eo);
    gemm_res_kernel<<<dim3(NO / BN, N_TOK / BM), 256, 0, stream>>>(x_bf, wt_bf, y);
    combine_kernel<<<N_TOK, 256, 0, stream>>>(y, eo, pair_slot, tok_g);
}

// Round 3
// 403.050 us; speedup vs baseline: 1.6234x; 1.1106x over previous
//
#include <hip/hip_runtime.h>
#include <hip/hip_bf16.h>
#include <stdint.h>

// Problem constants (from reference setup_inputs)
#define N_TOK 4096
#define DIM   1024
#define NE    8
#define NH    2048
#define NO    1024

typedef __attribute__((ext_vector_type(8))) short bf16x8;
typedef __attribute__((ext_vector_type(4))) float f32x4;

__device__ inline unsigned short f2bf(float f) {
    unsigned u = __float_as_uint(f);
    u += 0x7fffu + ((u >> 16) & 1u);   // round-to-nearest-even
    return (unsigned short)(u >> 16);
}

__device__ inline void async_copy16(const void* g, void* l) {
    __builtin_amdgcn_global_load_lds(
        (const __attribute__((address_space(1))) void*)g,
        (__attribute__((address_space(3))) void*)l, 16, 0, 0);
}

// ---------------- fused layernorm + gating (NO atomics) ----------------
// one block (256 thr) per token row
__global__ __launch_bounds__(256) void ln_gate_kernel(
    const float* __restrict__ x, const float* __restrict__ nw,
    const float* __restrict__ nb, const float* __restrict__ eps_p,
    const float* __restrict__ wg,
    unsigned short* __restrict__ xn_bf, unsigned short* __restrict__ x_bf,
    int* __restrict__ tok_e, float* __restrict__ tok_g)
{
    int n = blockIdx.x;
    int t = threadIdx.x;
    int lane = t & 63, wv = t >> 6;

    const float4 xv = ((const float4*)(x + (size_t)n * DIM))[t];
    float s  = xv.x + xv.y + xv.z + xv.w;
    float s2 = xv.x*xv.x + xv.y*xv.y + xv.z*xv.z + xv.w*xv.w;
    #pragma unroll
    for (int o = 32; o > 0; o >>= 1) {
        s  += __shfl_down(s, o);
        s2 += __shfl_down(s2, o);
    }
    __shared__ float rs[4], rs2[4];
    __shared__ float gred[4][NE];
    if (lane == 0) { rs[wv] = s; rs2[wv] = s2; }
    __syncthreads();
    float S  = rs[0] + rs[1] + rs[2] + rs[3];
    float S2 = rs2[0] + rs2[1] + rs2[2] + rs2[3];
    const float inv = 1.0f / (float)DIM;
    float mu = S * inv;
    float var = fmaxf(S2 * inv - mu * mu, 0.0f);   // biased, like F.layer_norm
    float rstd = rsqrtf(var + eps_p[0]);

    float4 w4 = ((const float4*)nw)[t];
    float4 b4 = ((const float4*)nb)[t];
    float xn0 = (xv.x - mu) * rstd * w4.x + b4.x;
    float xn1 = (xv.y - mu) * rstd * w4.y + b4.y;
    float xn2 = (xv.z - mu) * rstd * w4.z + b4.z;
    float xn3 = (xv.w - mu) * rstd * w4.w + b4.w;

    ushort4 pn; pn.x = f2bf(xn0); pn.y = f2bf(xn1); pn.z = f2bf(xn2); pn.w = f2bf(xn3);
    ((ushort4*)(xn_bf + (size_t)n * DIM))[t] = pn;
    ushort4 px; px.x = f2bf(xv.x); px.y = f2bf(xv.y); px.z = f2bf(xv.z); px.w = f2bf(xv.w);
    ((ushort4*)(x_bf + (size_t)n * DIM))[t] = px;

    // gating logits: x_norm (fp32) @ w_gate [D][E]
    float acc[NE];
    #pragma unroll
    for (int e = 0; e < NE; ++e) acc[e] = 0.0f;
    float xns[4] = {xn0, xn1, xn2, xn3};
    const float4* wgp = (const float4*)(wg + (size_t)(4 * t) * NE);
    #pragma unroll
    for (int j = 0; j < 4; ++j) {
        float4 w0 = wgp[2 * j], w1 = wgp[2 * j + 1];
        float xj = xns[j];
        acc[0] += xj * w0.x; acc[1] += xj * w0.y; acc[2] += xj * w0.z; acc[3] += xj * w0.w;
        acc[4] += xj * w1.x; acc[5] += xj * w1.y; acc[6] += xj * w1.z; acc[7] += xj * w1.w;
    }
    #pragma unroll
    for (int o = 32; o > 0; o >>= 1) {
        #pragma unroll
        for (int e = 0; e < NE; ++e) acc[e] += __shfl_down(acc[e], o);
    }
    if (lane == 0) {
        #pragma unroll
        for (int e = 0; e < NE; ++e) gred[wv][e] = acc[e];
    }
    __syncthreads();
    if (t == 0) {
        float lg[NE];
        float nrm2 = 0.0f;
        #pragma unroll
        for (int e = 0; e < NE; ++e) {
            lg[e] = gred[0][e] + gred[1][e] + gred[2][e] + gred[3][e];
            nrm2 += lg[e] * lg[e];
        }
        float den = fmaxf(sqrtf(nrm2), 1e-12f);
        float linv = 1.0f / den;
        #pragma unroll
        for (int e = 0; e < NE; ++e) lg[e] *= linv;
        float mx = lg[0];
        #pragma unroll
        for (int e = 1; e < NE; ++e) mx = fmaxf(mx, lg[e]);
        float p[NE], ps = 0.0f;
        #pragma unroll
        for (int e = 0; e < NE; ++e) { p[e] = expf(lg[e] - mx); ps += p[e]; }
        float pinv = 1.0f / ps;
        #pragma unroll
        for (int e = 0; e < NE; ++e) p[e] *= pinv;
        // top-2, lowest-index wins ties (jax.lax.top_k semantics)
        int i0 = 0; float b0 = lg[0];
        #pragma unroll
        for (int e = 1; e < NE; ++e) if (lg[e] > b0) { b0 = lg[e]; i0 = e; }
        int i1 = -1; float b1 = -3.0e38f;
        #pragma unroll
        for (int e = 0; e < NE; ++e) if (e != i0 && lg[e] > b1) { b1 = lg[e]; i1 = e; }
        tok_e[2 * n] = i0; tok_e[2 * n + 1] = i1;
        tok_g[2 * n] = p[i0]; tok_g[2 * n + 1] = p[i1];
    }
}

// ---------------- fp32 -> bf16 bulk convert ----------------
__global__ void cvt_bf16_kernel(const float* __restrict__ src,
                                unsigned short* __restrict__ dst, int n4) {
    int i = blockIdx.x * blockDim.x + threadIdx.x;
    if (i < n4) {
        float4 v = ((const float4*)src)[i];
        ushort4 o; o.x = f2bf(v.x); o.y = f2bf(v.y); o.z = f2bf(v.z); o.w = f2bf(v.w);
        ((ushort4*)dst)[i] = o;
    }
}

// ---------------- output_weight [D][O] -> bf16 [O][D] ----------------
__global__ void transpose_cvt_kernel(const float* __restrict__ w,
                                     unsigned short* __restrict__ wt) {
    __shared__ float tile[32][33];
    int tx = threadIdx.x, ty = threadIdx.y;
    int o0 = blockIdx.x * 32, d0 = blockIdx.y * 32;
    tile[ty][tx] = w[(size_t)(d0 + ty) * NO + o0 + tx];
    __syncthreads();
    wt[(size_t)(o0 + ty) * DIM + d0 + tx] = f2bf(tile[tx][ty]);
}

// ---------------- count + finalize: histogram reduce, offsets, loss ----------------
__device__ inline float cv_sq(const float* v) {
    float m = 0.0f;
    for (int e = 0; e < NE; ++e) m += v[e];
    m *= (1.0f / NE);
    float s = 0.0f;
    for (int e = 0; e < NE; ++e) { float d = v[e] - m; s += d * d; }
    s *= (1.0f / (NE - 1));          // ddof=1
    return s / (m * m + 1e-6f);
}

// single block, 1024 threads
__global__ __launch_bounds__(1024) void count_finalize_kernel(
    const int* __restrict__ tok_e, const float* __restrict__ tok_g,
    int* __restrict__ counts, int* __restrict__ offsets,
    int* __restrict__ cursor_pad, float* __restrict__ out_tail)
{
    int t = threadIdx.x;
    int lane = t & 63, wv = t >> 6;   // 16 waves
    int lc[NE]; float li[NE];
    #pragma unroll
    for (int e = 0; e < NE; ++e) { lc[e] = 0; li[e] = 0.0f; }
    const int4* ep = (const int4*)(tok_e) + 2 * t;
    const float4* gp = (const float4*)(tok_g) + 2 * t;
    #pragma unroll
    for (int q = 0; q < 2; ++q) {
        int4 e4 = ep[q]; float4 g4 = gp[q];
        lc[e4.x]++; li[e4.x] += g4.x;
        lc[e4.y]++; li[e4.y] += g4.y;
        lc[e4.z]++; li[e4.z] += g4.z;
        lc[e4.w]++; li[e4.w] += g4.w;
    }
    #pragma unroll
    for (int o = 32; o > 0; o >>= 1) {
        #pragma unroll
        for (int e = 0; e < NE; ++e) {
            lc[e] += __shfl_down(lc[e], o);
            li[e] += __shfl_down(li[e], o);
        }
    }
    __shared__ int   sc[16][NE];
    __shared__ float sf[16][NE];
    if (lane == 0) {
        #pragma unroll
        for (int e = 0; e < NE; ++e) { sc[wv][e] = lc[e]; sf[wv][e] = li[e]; }
    }
    __syncthreads();
    if (t == 0) {
        float lif[NE], lcf[NE];
        int off = 0;
        for (int e = 0; e < NE; ++e) {
            int c = 0; float im = 0.0f;
            for (int w = 0; w < 16; ++w) { c += sc[w][e]; im += sf[w][e]; }
            counts[e] = c;
            offsets[e] = off;
            cursor_pad[e * 32] = off;   // one 128B line per expert
            off += c;
            lcf[e] = (float)c; lif[e] = im;
        }
        float tot = (float)off;
        out_tail[0] = 0.01f * (cv_sq(lif) + cv_sq(lcf));     // loss
        for (int e = 0; e < NE; ++e) out_tail[1 + e] = lcf[e] / tot;  // gate_fraction
    }
}

// ---------------- hierarchical scatter (few global atomics) ----------------
__global__ __launch_bounds__(256) void scatter_kernel(
    const int* __restrict__ tok_e, int* __restrict__ cursor_pad,
    int* __restrict__ rowsbuf, int* __restrict__ pair_slot)
{
    __shared__ int lhist[NE];
    __shared__ int lbase[NE];
    int t = threadIdx.x;
    int tok0 = blockIdx.x * 512 + 2 * t;     // 2 tokens per thread -> int4
    if (t < NE) lhist[t] = 0;
    __syncthreads();
    int4 e4 = *(const int4*)(tok_e + 2 * tok0);
    int r0 = atomicAdd(&lhist[e4.x], 1);
    int r1 = atomicAdd(&lhist[e4.y], 1);
    int r2 = atomicAdd(&lhist[e4.z], 1);
    int r3 = atomicAdd(&lhist[e4.w], 1);
    __syncthreads();
    if (t < NE) lbase[t] = atomicAdd(&cursor_pad[t * 32], lhist[t]);
    __syncthreads();
    int s0 = lbase[e4.x] + r0;
    int s1 = lbase[e4.y] + r1;
    int s2 = lbase[e4.z] + r2;
    int s3 = lbase[e4.w] + r3;
    rowsbuf[s0] = tok0;     rowsbuf[s1] = tok0;
    rowsbuf[s2] = tok0 + 1; rowsbuf[s3] = tok0 + 1;
    *(int4*)(pair_slot + 2 * tok0) = (int4){s0, s1, s2, s3};
}

// ---------------- GEMM kernels ----------------
// LDS layout (all GEMMs): [row][64 shorts]; logical 16B-slot s of row r stored
// at physical slot s ^ (r & 7)  -> bank-conflict-free wave64 ds_read_b128.
// Staging implements this by XORing the global source column slot; the
// global_load_lds LDS destination stays lane-contiguous (m104 constraint).
#define BK 64

// GEMM1: 128x128 tile. h[slot][col] = silu(xn[token] . wh[e][col] + bias)
__global__ __launch_bounds__(256) void gemm1_kernel(
    const unsigned short* __restrict__ xn,   // [N][D] bf16
    const unsigned short* __restrict__ wh,   // [E][H][D] bf16
    const float* __restrict__ hb,            // [E][H]
    const int* __restrict__ rowsbuf,
    const int* __restrict__ counts, const int* __restrict__ offsets,
    unsigned short* __restrict__ hbuf)       // [2N][H] bf16
{
    int e = blockIdx.z;
    int count = counts[e];
    int tm = blockIdx.y, tn = blockIdx.x;
    if (tm * 128 >= count) return;
    int off = offsets[e];

    __shared__ alignas(16) short As[128 * BK];
    __shared__ alignas(16) short Bs[128 * BK];

    int t = threadIdx.x;
    int c = t & 7, rl = t >> 3;
    int csw = (c ^ (rl & 7)) * 8;            // swizzled source column (shorts)
    const unsigned short* aptr[4];
    const unsigned short* bptr[4];
    #pragma unroll
    for (int p = 0; p < 4; ++p) {
        int mrow = tm * 128 + p * 32 + rl;
        int mc = mrow < count ? mrow : count - 1;
        int token = rowsbuf[off + mc];
        aptr[p] = xn + (size_t)token * DIM;
        bptr[p] = wh + ((size_t)e * NH + tn * 128 + p * 32 + rl) * DIM;
    }

    int lane = t & 63, wvi = t >> 6;
    int wm = (wvi & 1) * 64, wn = (wvi >> 1) * 64;
    int l15 = lane & 15, q = lane >> 4, sw = l15 & 7;

    f32x4 acc[4][4];
    #pragma unroll
    for (int i = 0; i < 4; ++i)
        #pragma unroll
        for (int j = 0; j < 4; ++j) acc[i][j] = (f32x4){0.f, 0.f, 0.f, 0.f};

    for (int kt = 0; kt < DIM / BK; ++kt) {
        int kb = kt * BK + csw;
        #pragma unroll
        for (int p = 0; p < 4; ++p)
            async_copy16(aptr[p] + kb, (char*)As + p * 4096 + t * 16);
        #pragma unroll
        for (int p = 0; p < 4; ++p)
            async_copy16(bptr[p] + kb, (char*)Bs + p * 4096 + t * 16);
        __syncthreads();
        #pragma unroll
        for (int ks = 0; ks < 2; ++ks) {
            int ph = ((ks * 4 + q) ^ sw) * 8;
            bf16x8 af[4], bfr[4];
            #pragma unroll
            for (int i = 0; i < 4; ++i)
                af[i] = *(const bf16x8*)&As[(wm + i * 16 + l15) * BK + ph];
            #pragma unroll
            for (int j = 0; j < 4; ++j)
                bfr[j] = *(const bf16x8*)&Bs[(wn + j * 16 + l15) * BK + ph];
            #pragma unroll
            for (int i = 0; i < 4; ++i)
                #pragma unroll
                for (int j = 0; j < 4; ++j)
                    acc[i][j] = __builtin_amdgcn_mfma_f32_16x16x32_bf16(af[i], bfr[j], acc[i][j], 0, 0, 0);
        }
        __syncthreads();
    }

    int q4 = (lane >> 4) * 4;
    #pragma unroll
    for (int i = 0; i < 4; ++i) {
        #pragma unroll
        for (int r = 0; r < 4; ++r) {
            int m = tm * 128 + wm + i * 16 + q4 + r;
            if (m < count) {
                size_t rowbase = (size_t)(off + m) * NH;
                #pragma unroll
                for (int j = 0; j < 4; ++j) {
                    int col = tn * 128 + wn + j * 16 + l15;
                    float v = acc[i][j][r] + hb[e * NH + col];
                    v = v / (1.0f + __expf(-v));           // silu
                    hbuf[rowbase + col] = f2bf(v);
                }
            }
        }
    }
}

// GEMM2: 128x64 tile (more blocks -> occupancy). eo = hbuf . wo^T + bias
__global__ __launch_bounds__(256) void gemm2_kernel(
    const unsigned short* __restrict__ hbuf,  // [2N][H] bf16
    const unsigned short* __restrict__ wo,    // [E][O][H] bf16
    const float* __restrict__ ob,             // [E][O]
    const int* __restrict__ counts, const int* __restrict__ offsets,
    float* __restrict__ eo)                   // [2N][O] fp32
{
    int e = blockIdx.z;
    int count = counts[e];
    int tm = blockIdx.y, tn = blockIdx.x;
    if (tm * 128 >= count) return;
    int off = offsets[e];

    __shared__ alignas(16) short As[128 * BK];
    __shared__ alignas(16) short Bs[64 * BK];

    int t = threadIdx.x;
    int c = t & 7, rl = t >> 3;
    int csw = (c ^ (rl & 7)) * 8;
    const unsigned short* aptr[4];
    const unsigned short* bptr[2];
    #pragma unroll
    for (int p = 0; p < 4; ++p) {
        int mrow = tm * 128 + p * 32 + rl;
        int mc = mrow < count ? mrow : count - 1;
        aptr[p] = hbuf + (size_t)(off + mc) * NH;
    }
    #pragma unroll
    for (int p = 0; p < 2; ++p)
        bptr[p] = wo + ((size_t)e * NO + tn * 64 + p * 32 + rl) * NH;

    int lane = t & 63, wvi = t >> 6;
    int wm = (wvi & 1) * 64, wn = (wvi >> 1) * 32;
    int l15 = lane & 15, q = lane >> 4, sw = l15 & 7;

    f32x4 acc[4][2];
    #pragma unroll
    for (int i = 0; i < 4; ++i)
        #pragma unroll
        for (int j = 0; j < 2; ++j) acc[i][j] = (f32x4){0.f, 0.f, 0.f, 0.f};

    for (int kt = 0; kt < NH / BK; ++kt) {
        int kb = kt * BK + csw;
        #pragma unroll
        for (int p = 0; p < 4; ++p)
            async_copy16(aptr[p] + kb, (char*)As + p * 4096 + t * 16);
        #pragma unroll
        for (int p = 0; p < 2; ++p)
            async_copy16(bptr[p] + kb, (char*)Bs + p * 4096 + t * 16);
        __syncthreads();
        #pragma unroll
        for (int ks = 0; ks < 2; ++ks) {
            int ph = ((ks * 4 + q) ^ sw) * 8;
            bf16x8 af[4], bfr[2];
            #pragma unroll
            for (int i = 0; i < 4; ++i)
                af[i] = *(const bf16x8*)&As[(wm + i * 16 + l15) * BK + ph];
            #pragma unroll
            for (int j = 0; j < 2; ++j)
                bfr[j] = *(const bf16x8*)&Bs[(wn + j * 16 + l15) * BK + ph];
            #pragma unroll
            for (int i = 0; i < 4; ++i)
                #pragma unroll
                for (int j = 0; j < 2; ++j)
                    acc[i][j] = __builtin_amdgcn_mfma_f32_16x16x32_bf16(af[i], bfr[j], acc[i][j], 0, 0, 0);
        }
        __syncthreads();
    }

    int q4 = (lane >> 4) * 4;
    #pragma unroll
    for (int i = 0; i < 4; ++i) {
        #pragma unroll
        for (int r = 0; r < 4; ++r) {
            int m = tm * 128 + wm + i * 16 + q4 + r;
            if (m < count) {
                size_t rowbase = (size_t)(off + m) * NO;
                #pragma unroll
                for (int j = 0; j < 2; ++j) {
                    int col = tn * 64 + wn + j * 16 + l15;
                    eo[rowbase + col] = acc[i][j][r] + ob[e * NO + col];
                }
            }
        }
    }
}

// Residual GEMM: 64x128 tile (512 blocks). y[n][o] = x_bf[n] . woutT[o]
__global__ __launch_bounds__(256) void gemm_res_kernel(
    const unsigned short* __restrict__ xb,   // [N][D] bf16
    const unsigned short* __restrict__ wt,   // [O][D] bf16
    float* __restrict__ y)                   // [N][O] fp32
{
    int tm = blockIdx.y, tn = blockIdx.x;
    __shared__ alignas(16) short As[64 * BK];
    __shared__ alignas(16) short Bs[128 * BK];

    int t = threadIdx.x;
    int c = t & 7, rl = t >> 3;
    int csw = (c ^ (rl & 7)) * 8;
    const unsigned short* aptr[2];
    const unsigned short* bptr[4];
    #pragma unroll
    for (int p = 0; p < 2; ++p)
        aptr[p] = xb + (size_t)(tm * 64 + p * 32 + rl) * DIM;
    #pragma unroll
    for (int p = 0; p < 4; ++p)
        bptr[p] = wt + (size_t)(tn * 128 + p * 32 + rl) * DIM;

    int lane = t & 63, wvi = t >> 6;
    int wm = (wvi & 1) * 32, wn = (wvi >> 1) * 64;
    int l15 = lane & 15, q = lane >> 4, sw = l15 & 7;

    f32x4 acc[2][4];
    #pragma unroll
    for (int i = 0; i < 2; ++i)
        #pragma unroll
        for (int j = 0; j < 4; ++j) acc[i][j] = (f32x4){0.f, 0.f, 0.f, 0.f};

    for (int kt = 0; kt < DIM / BK; ++kt) {
        int kb = kt * BK + csw;
        #pragma unroll
        for (int p = 0; p < 2; ++p)
            async_copy16(aptr[p] + kb, (char*)As + p * 4096 + t * 16);
        #pragma unroll
        for (int p = 0; p < 4; ++p)
            async_copy16(bptr[p] + kb, (char*)Bs + p * 4096 + t * 16);
        __syncthreads();
        #pragma unroll
        for (int ks = 0; ks < 2; ++ks) {
            int ph = ((ks * 4 + q) ^ sw) * 8;
            bf16x8 af[2], bfr[4];
            #pragma unroll
            for (int i = 0; i < 2; ++i)
                af[i] = *(const bf16x8*)&As[(wm + i * 16 + l15) * BK + ph];
            #pragma unroll
            for (int j = 0; j < 4; ++j)
                bfr[j] = *(const bf16x8*)&Bs[(wn + j * 16 + l15) * BK + ph];
            #pragma unroll
            for (int i = 0; i < 2; ++i)
                #pragma unroll
                for (int j = 0; j < 4; ++j)
                    acc[i][j] = __builtin_amdgcn_mfma_f32_16x16x32_bf16(af[i], bfr[j], acc[i][j], 0, 0, 0);
        }
        __syncthreads();
    }

    int q4 = (lane >> 4) * 4;
    #pragma unroll
    for (int i = 0; i < 2; ++i) {
        #pragma unroll
        for (int r = 0; r < 4; ++r) {
            int row = tm * 64 + wm + i * 16 + q4 + r;
            #pragma unroll
            for (int j = 0; j < 4; ++j) {
                int col = tn * 128 + wn + j * 16 + l15;
                y[(size_t)row * NO + col] = acc[i][j][r];
            }
        }
    }
}

// ---------------- gated combine: y += g0*eo[p0] + g1*eo[p1] ----------------
__global__ __launch_bounds__(256) void combine_kernel(
    float* __restrict__ y, const float* __restrict__ eo,
    const int* __restrict__ pair_slot, const float* __restrict__ tok_g)
{
    int n = blockIdx.x, t = threadIdx.x;
    int s0 = pair_slot[2 * n], s1 = pair_slot[2 * n + 1];
    float g0 = tok_g[2 * n], g1 = tok_g[2 * n + 1];
    float4 a = ((const float4*)(eo + (size_t)s0 * NO))[t];
    float4 b = ((const float4*)(eo + (size_t)s1 * NO))[t];
    float4* yp = (float4*)(y + (size_t)n * NO) + t;
    float4 v = *yp;
    v.x += g0 * a.x + g1 * b.x;
    v.y += g0 * a.y + g1 * b.y;
    v.z += g0 * a.z + g1 * b.z;
    v.w += g0 * a.w + g1 * b.w;
    *yp = v;
}

extern "C" void kernel_launch(void* const* d_in, const int* in_sizes, int n_in,
                              void* d_out, int out_size, void* d_ws, size_t ws_size,
                              hipStream_t stream) {
    const float* x    = (const float*)d_in[0];
    const float* nw   = (const float*)d_in[6];
    const float* nb   = (const float*)d_in[7];
    const float* eps  = (const float*)d_in[8];
    const float* wg   = (const float*)d_in[9];
    const float* whw  = (const float*)d_in[10];
    const float* whb  = (const float*)d_in[11];
    const float* wow  = (const float*)d_in[12];
    const float* wob  = (const float*)d_in[13];
    const float* wout = (const float*)d_in[14];

    char* ws = (char*)d_ws;
    // workspace layout (bytes)
    unsigned short* xn_bf = (unsigned short*)(ws + 0);          //  8,388,608
    unsigned short* x_bf  = (unsigned short*)(ws + 8388608);    //  8,388,608
    unsigned short* wh_bf = (unsigned short*)(ws + 16777216);   // 33,554,432
    float*          eo    = (float*)(ws + 16777216);            // alias: used after gemm1 done
    unsigned short* wo_bf = (unsigned short*)(ws + 50331648);   // 33,554,432
    unsigned short* wt_bf = (unsigned short*)(ws + 83886080);   //  2,097,152
    unsigned short* hbuf  = (unsigned short*)(ws + 85983232);   // 33,554,432
    char* meta = ws + 119537664;
    int*   counts     = (int*)(meta + 0);
    int*   offsets    = (int*)(meta + 128);
    int*   cursor_pad = (int*)(meta + 256);     // 8 experts x 128B stride
    int*   tok_e      = (int*)(meta + 2048);
    float* tok_g      = (float*)(meta + 2048 + 32768);
    int*   rowsbuf    = (int*)(meta + 2048 + 65536);
    int*   pair_slot  = (int*)(meta + 2048 + 98304);

    float* y = (float*)d_out;
    float* out_tail = y + (size_t)N_TOK * NO;   // loss, then gate_fraction[8]

    ln_gate_kernel<<<N_TOK, 256, 0, stream>>>(x, nw, nb, eps, wg, xn_bf, x_bf,
                                              tok_e, tok_g);
    {
        int n4 = NE * NH * DIM / 4;   // 4,194,304 (same for wo: E*O*H)
        cvt_bf16_kernel<<<n4 / 256, 256, 0, stream>>>(whw, wh_bf, n4);
        cvt_bf16_kernel<<<n4 / 256, 256, 0, stream>>>(wow, wo_bf, n4);
    }
    transpose_cvt_kernel<<<dim3(NO / 32, DIM / 32), dim3(32, 32), 0, stream>>>(wout, wt_bf);
    count_finalize_kernel<<<1, 1024, 0, stream>>>(tok_e, tok_g, counts, offsets,
                                                  cursor_pad, out_tail);
    scatter_kernel<<<N_TOK / 512, 256, 0, stream>>>(tok_e, cursor_pad, rowsbuf, pair_slot);
    gemm1_kernel<<<dim3(NH / 128, N_TOK / 128, NE), 256, 0, stream>>>(
        xn_bf, wh_bf, whb, rowsbuf, counts, offsets, hbuf);
    gemm2_kernel<<<dim3(NO / 64, N_TOK / 128, NE), 256, 0, stream>>>(
        hbuf, wo_bf, wob, counts, offsets, eo);
    gemm_res_kernel<<<dim3(NO / 128, N_TOK / 64), 256, 0, stream>>>(x_bf, wt_bf, y);
    combine_kernel<<<N_TOK, 256, 0, stream>>>(y, eo, pair_slot, tok_g);
}

// Round 4
// 389.074 us; speedup vs baseline: 1.6817x; 1.0359x over previous
//
#include <hip/hip_runtime.h>
#include <hip/hip_bf16.h>
#include <stdint.h>

// Problem constants (from reference setup_inputs)
#define N_TOK 4096
#define DIM   1024
#define NE    8
#define NH    2048
#define NO    1024

typedef __attribute__((ext_vector_type(8))) short bf16x8;
typedef __attribute__((ext_vector_type(16))) float f32x16;

__device__ inline unsigned short f2bf(float f) {
    unsigned u = __float_as_uint(f);
    u += 0x7fffu + ((u >> 16) & 1u);   // round-to-nearest-even
    return (unsigned short)(u >> 16);
}

__device__ inline void async_copy16(const void* g, void* l) {
    __builtin_amdgcn_global_load_lds(
        (const __attribute__((address_space(1))) void*)g,
        (__attribute__((address_space(3))) void*)l, 16, 0, 0);
}

// ---------------- fused layernorm + gating (NO atomics) ----------------
// one block (256 thr) per token row
__global__ __launch_bounds__(256) void ln_gate_kernel(
    const float* __restrict__ x, const float* __restrict__ nw,
    const float* __restrict__ nb, const float* __restrict__ eps_p,
    const float* __restrict__ wg,
    unsigned short* __restrict__ xn_bf, unsigned short* __restrict__ x_bf,
    int* __restrict__ tok_e, float* __restrict__ tok_g)
{
    int n = blockIdx.x;
    int t = threadIdx.x;
    int lane = t & 63, wv = t >> 6;

    const float4 xv = ((const float4*)(x + (size_t)n * DIM))[t];
    float s  = xv.x + xv.y + xv.z + xv.w;
    float s2 = xv.x*xv.x + xv.y*xv.y + xv.z*xv.z + xv.w*xv.w;
    #pragma unroll
    for (int o = 32; o > 0; o >>= 1) {
        s  += __shfl_down(s, o);
        s2 += __shfl_down(s2, o);
    }
    __shared__ float rs[4], rs2[4];
    __shared__ float gred[4][NE];
    if (lane == 0) { rs[wv] = s; rs2[wv] = s2; }
    __syncthreads();
    float S  = rs[0] + rs[1] + rs[2] + rs[3];
    float S2 = rs2[0] + rs2[1] + rs2[2] + rs2[3];
    const float inv = 1.0f / (float)DIM;
    float mu = S * inv;
    float var = fmaxf(S2 * inv - mu * mu, 0.0f);   // biased, like F.layer_norm
    float rstd = rsqrtf(var + eps_p[0]);

    float4 w4 = ((const float4*)nw)[t];
    float4 b4 = ((const float4*)nb)[t];
    float xn0 = (xv.x - mu) * rstd * w4.x + b4.x;
    float xn1 = (xv.y - mu) * rstd * w4.y + b4.y;
    float xn2 = (xv.z - mu) * rstd * w4.z + b4.z;
    float xn3 = (xv.w - mu) * rstd * w4.w + b4.w;

    ushort4 pn; pn.x = f2bf(xn0); pn.y = f2bf(xn1); pn.z = f2bf(xn2); pn.w = f2bf(xn3);
    ((ushort4*)(xn_bf + (size_t)n * DIM))[t] = pn;
    ushort4 px; px.x = f2bf(xv.x); px.y = f2bf(xv.y); px.z = f2bf(xv.z); px.w = f2bf(xv.w);
    ((ushort4*)(x_bf + (size_t)n * DIM))[t] = px;

    // gating logits: x_norm (fp32) @ w_gate [D][E]
    float acc[NE];
    #pragma unroll
    for (int e = 0; e < NE; ++e) acc[e] = 0.0f;
    float xns[4] = {xn0, xn1, xn2, xn3};
    const float4* wgp = (const float4*)(wg + (size_t)(4 * t) * NE);
    #pragma unroll
    for (int j = 0; j < 4; ++j) {
        float4 w0 = wgp[2 * j], w1 = wgp[2 * j + 1];
        float xj = xns[j];
        acc[0] += xj * w0.x; acc[1] += xj * w0.y; acc[2] += xj * w0.z; acc[3] += xj * w0.w;
        acc[4] += xj * w1.x; acc[5] += xj * w1.y; acc[6] += xj * w1.z; acc[7] += xj * w1.w;
    }
    #pragma unroll
    for (int o = 32; o > 0; o >>= 1) {
        #pragma unroll
        for (int e = 0; e < NE; ++e) acc[e] += __shfl_down(acc[e], o);
    }
    if (lane == 0) {
        #pragma unroll
        for (int e = 0; e < NE; ++e) gred[wv][e] = acc[e];
    }
    __syncthreads();
    if (t == 0) {
        float lg[NE];
        float nrm2 = 0.0f;
        #pragma unroll
        for (int e = 0; e < NE; ++e) {
            lg[e] = gred[0][e] + gred[1][e] + gred[2][e] + gred[3][e];
            nrm2 += lg[e] * lg[e];
        }
        float den = fmaxf(sqrtf(nrm2), 1e-12f);
        float linv = 1.0f / den;
        #pragma unroll
        for (int e = 0; e < NE; ++e) lg[e] *= linv;
        float mx = lg[0];
        #pragma unroll
        for (int e = 1; e < NE; ++e) mx = fmaxf(mx, lg[e]);
        float p[NE], ps = 0.0f;
        #pragma unroll
        for (int e = 0; e < NE; ++e) { p[e] = expf(lg[e] - mx); ps += p[e]; }
        float pinv = 1.0f / ps;
        #pragma unroll
        for (int e = 0; e < NE; ++e) p[e] *= pinv;
        // top-2, lowest-index wins ties (jax.lax.top_k semantics)
        int i0 = 0; float b0 = lg[0];
        #pragma unroll
        for (int e = 1; e < NE; ++e) if (lg[e] > b0) { b0 = lg[e]; i0 = e; }
        int i1 = -1; float b1 = -3.0e38f;
        #pragma unroll
        for (int e = 0; e < NE; ++e) if (e != i0 && lg[e] > b1) { b1 = lg[e]; i1 = e; }
        tok_e[2 * n] = i0; tok_e[2 * n + 1] = i1;
        tok_g[2 * n] = p[i0]; tok_g[2 * n + 1] = p[i1];
    }
}

// ---------------- fp32 -> bf16 bulk convert (both expert weights) ----------------
__global__ void cvt2_bf16_kernel(const float* __restrict__ a, unsigned short* __restrict__ da,
                                 const float* __restrict__ b, unsigned short* __restrict__ db,
                                 int n4each) {
    int i = blockIdx.x * blockDim.x + threadIdx.x;
    const float4* s; ushort4* d; int j;
    if (i < n4each) { s = (const float4*)a; d = (ushort4*)da; j = i; }
    else            { s = (const float4*)b; d = (ushort4*)db; j = i - n4each; }
    float4 v = s[j];
    ushort4 o; o.x = f2bf(v.x); o.y = f2bf(v.y); o.z = f2bf(v.z); o.w = f2bf(v.w);
    d[j] = o;
}

// ---------------- output_weight [D][O] -> bf16 [O][D] ----------------
__global__ void transpose_cvt_kernel(const float* __restrict__ w,
                                     unsigned short* __restrict__ wt) {
    __shared__ float tile[32][33];
    int tx = threadIdx.x, ty = threadIdx.y;
    int o0 = blockIdx.x * 32, d0 = blockIdx.y * 32;
    tile[ty][tx] = w[(size_t)(d0 + ty) * NO + o0 + tx];
    __syncthreads();
    wt[(size_t)(o0 + ty) * DIM + d0 + tx] = f2bf(tile[tx][ty]);
}

// ---------------- fused routing: histogram + offsets + loss + scatter ----------------
__device__ inline float cv_sq(const float* v) {
    float m = 0.0f;
    for (int e = 0; e < NE; ++e) m += v[e];
    m *= (1.0f / NE);
    float s = 0.0f;
    for (int e = 0; e < NE; ++e) { float d = v[e] - m; s += d * d; }
    s *= (1.0f / (NE - 1));          // ddof=1
    return s / (m * m + 1e-6f);
}

// 8 blocks x 256 threads; block b scatters chunk [b*1024, b*1024+1024) of the
// 8192 (token,k) entries. Every block redundantly histograms all entries
// (32 KB read - trivial) so there is NO inter-block communication at all.
__global__ __launch_bounds__(256) void route_kernel(
    const int* __restrict__ tok_e, const float* __restrict__ tok_g,
    int* __restrict__ counts, int* __restrict__ offsets,
    int* __restrict__ rowsbuf, int* __restrict__ pair_slot,
    float* __restrict__ out_tail)
{
    int b = blockIdx.x, t = threadIdx.x;
    int lane = t & 63, wv = t >> 6;       // 4 waves
    int chunk0 = b * 1024;

    // stripe [t*32, t*32+32): per-thread histogram (full + prior-to-chunk + gate sum)
    int lc[NE]; float li[NE];
    #pragma unroll
    for (int e = 0; e < NE; ++e) { lc[e] = 0; li[e] = 0.0f; }
    int base = t * 32;
    #pragma unroll
    for (int q = 0; q < 8; ++q) {
        int4 e4 = *(const int4*)(tok_e + base + q * 4);
        float4 g4 = *(const float4*)(tok_g + base + q * 4);
        lc[e4.x]++; li[e4.x] += g4.x;
        lc[e4.y]++; li[e4.y] += g4.y;
        lc[e4.z]++; li[e4.z] += g4.z;
        lc[e4.w]++; li[e4.w] += g4.w;
    }
    int prior_flag = (base + 32 <= chunk0) ? 1 : 0;   // stripes never straddle chunk bounds
    int lp[NE];
    #pragma unroll
    for (int e = 0; e < NE; ++e) lp[e] = prior_flag ? lc[e] : 0;

    #pragma unroll
    for (int o = 32; o > 0; o >>= 1) {
        #pragma unroll
        for (int e = 0; e < NE; ++e) {
            lc[e] += __shfl_down(lc[e], o);
            lp[e] += __shfl_down(lp[e], o);
            li[e] += __shfl_down(li[e], o);
        }
    }
    __shared__ int   sc[4][NE], sp[4][NE];
    __shared__ float sf[4][NE];
    __shared__ int   lcur[NE];
    if (lane == 0) {
        #pragma unroll
        for (int e = 0; e < NE; ++e) { sc[wv][e] = lc[e]; sp[wv][e] = lp[e]; sf[wv][e] = li[e]; }
    }
    __syncthreads();
    if (t == 0) {
        int cnt[NE], pri[NE]; float imp[NE];
        for (int e = 0; e < NE; ++e) {
            cnt[e] = sc[0][e] + sc[1][e] + sc[2][e] + sc[3][e];
            pri[e] = sp[0][e] + sp[1][e] + sp[2][e] + sp[3][e];
            imp[e] = sf[0][e] + sf[1][e] + sf[2][e] + sf[3][e];
        }
        int off = 0;
        for (int e = 0; e < NE; ++e) {
            lcur[e] = off + pri[e];     // this chunk's starting cursor for expert e
            if (b == 0) { counts[e] = cnt[e]; offsets[e] = off; }
            off += cnt[e];
        }
        if (b == 0) {
            float lcf[NE], lif[NE];
            for (int e = 0; e < NE; ++e) { lcf[e] = (float)cnt[e]; lif[e] = imp[e]; }
            float tot = (float)off;
            out_tail[0] = 0.01f * (cv_sq(lif) + cv_sq(lcf));          // loss
            for (int e = 0; e < NE; ++e) out_tail[1 + e] = lcf[e] / tot;  // gate_fraction
        }
    }
    __syncthreads();

    // scatter this block's chunk: 4 entries (2 tokens) per thread
    int g0 = chunk0 + 4 * t;
    int4 e4 = *(const int4*)(tok_e + g0);
    int s0 = atomicAdd(&lcur[e4.x], 1);
    int s1 = atomicAdd(&lcur[e4.y], 1);
    int s2 = atomicAdd(&lcur[e4.z], 1);
    int s3 = atomicAdd(&lcur[e4.w], 1);
    int tok0 = g0 >> 1;
    rowsbuf[s0] = tok0;     rowsbuf[s1] = tok0;
    rowsbuf[s2] = tok0 + 1; rowsbuf[s3] = tok0 + 1;
    *(int4*)(pair_slot + g0) = (int4){s0, s1, s2, s3};
}

// ---------------- GEMM kernels (32x32x16 MFMA) ----------------
// LDS layout: [row][64 shorts]; logical 16B-slot s of row r stored at physical
// slot s ^ (r & 7) -> conflict-free wave64 ds_read_b128 (2 lanes/slot per
// 16-lane group). Staging XORs the global source column; global_load_lds LDS
// destination stays lane-contiguous (m104 constraint).
// Fragment maps (32x32x16 bf16): A/B lane holds row lane&31, k=(lane>>5)*8+j;
// C/D: col=lane&31, row=(reg&3)+8*(reg>>2)+4*(lane>>5)  [m74/m101].
#define BK 64

// GEMM1: 128x128 tile, wave = 2x2 blocks of 32x32.
__global__ __launch_bounds__(256) void gemm1_kernel(
    const unsigned short* __restrict__ xn,   // [N][D] bf16
    const unsigned short* __restrict__ wh,   // [E][H][D] bf16
    const float* __restrict__ hb,            // [E][H]
    const int* __restrict__ rowsbuf,
    const int* __restrict__ counts, const int* __restrict__ offsets,
    unsigned short* __restrict__ hbuf)       // [2N][H] bf16
{
    int e = blockIdx.z;
    int count = counts[e];
    int tm = blockIdx.y, tn = blockIdx.x;
    if (tm * 128 >= count) return;
    int off = offsets[e];

    __shared__ alignas(16) short As[128 * BK];
    __shared__ alignas(16) short Bs[128 * BK];

    int t = threadIdx.x;
    int c = t & 7, rl = t >> 3;
    int csw = (c ^ (rl & 7)) * 8;            // swizzled source column (shorts)
    const unsigned short* aptr[4];
    const unsigned short* bptr[4];
    #pragma unroll
    for (int p = 0; p < 4; ++p) {
        int mrow = tm * 128 + p * 32 + rl;
        int mc = mrow < count ? mrow : count - 1;
        int token = rowsbuf[off + mc];
        aptr[p] = xn + (size_t)token * DIM;
        bptr[p] = wh + ((size_t)e * NH + tn * 128 + p * 32 + rl) * DIM;
    }

    int lane = t & 63, wvi = t >> 6;
    int wm = (wvi & 1) * 64, wn = (wvi >> 1) * 64;
    int l31 = lane & 31, h = lane >> 5, sw = l31 & 7;

    f32x16 acc[2][2];
    #pragma unroll
    for (int i = 0; i < 2; ++i)
        #pragma unroll
        for (int j = 0; j < 2; ++j) acc[i][j] = (f32x16)(0.0f);

    for (int kt = 0; kt < DIM / BK; ++kt) {
        int kb = kt * BK + csw;
        #pragma unroll
        for (int p = 0; p < 4; ++p)
            async_copy16(aptr[p] + kb, (char*)As + p * 4096 + t * 16);
        #pragma unroll
        for (int p = 0; p < 4; ++p)
            async_copy16(bptr[p] + kb, (char*)Bs + p * 4096 + t * 16);
        __syncthreads();
        #pragma unroll
        for (int ks = 0; ks < 4; ++ks) {
            int ph = ((ks * 2 + h) ^ sw) * 8;
            bf16x8 af[2], bfr[2];
            #pragma unroll
            for (int i = 0; i < 2; ++i)
                af[i] = *(const bf16x8*)&As[(wm + i * 32 + l31) * BK + ph];
            #pragma unroll
            for (int j = 0; j < 2; ++j)
                bfr[j] = *(const bf16x8*)&Bs[(wn + j * 32 + l31) * BK + ph];
            #pragma unroll
            for (int i = 0; i < 2; ++i)
                #pragma unroll
                for (int j = 0; j < 2; ++j)
                    acc[i][j] = __builtin_amdgcn_mfma_f32_32x32x16_bf16(af[i], bfr[j], acc[i][j], 0, 0, 0);
        }
        __syncthreads();
    }

    #pragma unroll
    for (int i = 0; i < 2; ++i) {
        #pragma unroll
        for (int j = 0; j < 2; ++j) {
            int col = tn * 128 + wn + j * 32 + l31;
            float bias = hb[e * NH + col];
            #pragma unroll
            for (int r = 0; r < 16; ++r) {
                int row_d = (r & 3) + 8 * (r >> 2) + 4 * h;
                int m = tm * 128 + wm + i * 32 + row_d;
                if (m < count) {
                    float v = acc[i][j][r] + bias;
                    v = v / (1.0f + __expf(-v));           // silu
                    hbuf[(size_t)(off + m) * NH + col] = f2bf(v);
                }
            }
        }
    }
}

// GEMM2: 128x64 tile, wave = 2x1 blocks of 32x32. eo = hbuf . wo^T + bias
__global__ __launch_bounds__(256) void gemm2_kernel(
    const unsigned short* __restrict__ hbuf,  // [2N][H] bf16
    const unsigned short* __restrict__ wo,    // [E][O][H] bf16
    const float* __restrict__ ob,             // [E][O]
    const int* __restrict__ counts, const int* __restrict__ offsets,
    float* __restrict__ eo)                   // [2N][O] fp32
{
    int e = blockIdx.z;
    int count = counts[e];
    int tm = blockIdx.y, tn = blockIdx.x;
    if (tm * 128 >= count) return;
    int off = offsets[e];

    __shared__ alignas(16) short As[128 * BK];
    __shared__ alignas(16) short Bs[64 * BK];

    int t = threadIdx.x;
    int c = t & 7, rl = t >> 3;
    int csw = (c ^ (rl & 7)) * 8;
    const unsigned short* aptr[4];
    const unsigned short* bptr[2];
    #pragma unroll
    for (int p = 0; p < 4; ++p) {
        int mrow = tm * 128 + p * 32 + rl;
        int mc = mrow < count ? mrow : count - 1;
        aptr[p] = hbuf + (size_t)(off + mc) * NH;
    }
    #pragma unroll
    for (int p = 0; p < 2; ++p)
        bptr[p] = wo + ((size_t)e * NO + tn * 64 + p * 32 + rl) * NH;

    int lane = t & 63, wvi = t >> 6;
    int wm = (wvi & 1) * 64, wn = (wvi >> 1) * 32;
    int l31 = lane & 31, h = lane >> 5, sw = l31 & 7;

    f32x16 acc[2];
    #pragma unroll
    for (int i = 0; i < 2; ++i) acc[i] = (f32x16)(0.0f);

    for (int kt = 0; kt < NH / BK; ++kt) {
        int kb = kt * BK + csw;
        #pragma unroll
        for (int p = 0; p < 4; ++p)
            async_copy16(aptr[p] + kb, (char*)As + p * 4096 + t * 16);
        #pragma unroll
        for (int p = 0; p < 2; ++p)
            async_copy16(bptr[p] + kb, (char*)Bs + p * 4096 + t * 16);
        __syncthreads();
        #pragma unroll
        for (int ks = 0; ks < 4; ++ks) {
            int ph = ((ks * 2 + h) ^ sw) * 8;
            bf16x8 af[2], bfr;
            #pragma unroll
            for (int i = 0; i < 2; ++i)
                af[i] = *(const bf16x8*)&As[(wm + i * 32 + l31) * BK + ph];
            bfr = *(const bf16x8*)&Bs[(wn + l31) * BK + ph];
            #pragma unroll
            for (int i = 0; i < 2; ++i)
                acc[i] = __builtin_amdgcn_mfma_f32_32x32x16_bf16(af[i], bfr, acc[i], 0, 0, 0);
        }
        __syncthreads();
    }

    int col = tn * 64 + wn + l31;
    float bias = ob[e * NO + col];
    #pragma unroll
    for (int i = 0; i < 2; ++i) {
        #pragma unroll
        for (int r = 0; r < 16; ++r) {
            int row_d = (r & 3) + 8 * (r >> 2) + 4 * h;
            int m = tm * 128 + wm + i * 32 + row_d;
            if (m < count)
                eo[(size_t)(off + m) * NO + col] = acc[i][r] + bias;
        }
    }
}

// Residual GEMM: 64x128 tile, wave = 1x2 blocks of 32x32. y = x_bf . woutT
__global__ __launch_bounds__(256) void gemm_res_kernel(
    const unsigned short* __restrict__ xb,   // [N][D] bf16
    const unsigned short* __restrict__ wt,   // [O][D] bf16
    float* __restrict__ y)                   // [N][O] fp32
{
    int tm = blockIdx.y, tn = blockIdx.x;
    __shared__ alignas(16) short As[64 * BK];
    __shared__ alignas(16) short Bs[128 * BK];

    int t = threadIdx.x;
    int c = t & 7, rl = t >> 3;
    int csw = (c ^ (rl & 7)) * 8;
    const unsigned short* aptr[2];
    const unsigned short* bptr[4];
    #pragma unroll
    for (int p = 0; p < 2; ++p)
        aptr[p] = xb + (size_t)(tm * 64 + p * 32 + rl) * DIM;
    #pragma unroll
    for (int p = 0; p < 4; ++p)
        bptr[p] = wt + (size_t)(tn * 128 + p * 32 + rl) * DIM;

    int lane = t & 63, wvi = t >> 6;
    int wm = (wvi & 1) * 32, wn = (wvi >> 1) * 64;
    int l31 = lane & 31, h = lane >> 5, sw = l31 & 7;

    f32x16 acc[2];
    #pragma unroll
    for (int j = 0; j < 2; ++j) acc[j] = (f32x16)(0.0f);

    for (int kt = 0; kt < DIM / BK; ++kt) {
        int kb = kt * BK + csw;
        #pragma unroll
        for (int p = 0; p < 2; ++p)
            async_copy16(aptr[p] + kb, (char*)As + p * 4096 + t * 16);
        #pragma unroll
        for (int p = 0; p < 4; ++p)
            async_copy16(bptr[p] + kb, (char*)Bs + p * 4096 + t * 16);
        __syncthreads();
        #pragma unroll
        for (int ks = 0; ks < 4; ++ks) {
            int ph = ((ks * 2 + h) ^ sw) * 8;
            bf16x8 af, bfr[2];
            af = *(const bf16x8*)&As[(wm + l31) * BK + ph];
            #pragma unroll
            for (int j = 0; j < 2; ++j)
                bfr[j] = *(const bf16x8*)&Bs[(wn + j * 32 + l31) * BK + ph];
            #pragma unroll
            for (int j = 0; j < 2; ++j)
                acc[j] = __builtin_amdgcn_mfma_f32_32x32x16_bf16(af, bfr[j], acc[j], 0, 0, 0);
        }
        __syncthreads();
    }

    #pragma unroll
    for (int j = 0; j < 2; ++j) {
        int col = tn * 128 + wn + j * 32 + l31;
        #pragma unroll
        for (int r = 0; r < 16; ++r) {
            int row_d = (r & 3) + 8 * (r >> 2) + 4 * h;
            int row = tm * 64 + wm + row_d;
            y[(size_t)row * NO + col] = acc[j][r];
        }
    }
}

// ---------------- gated combine: y += g0*eo[p0] + g1*eo[p1] ----------------
__global__ __launch_bounds__(256) void combine_kernel(
    float* __restrict__ y, const float* __restrict__ eo,
    const int* __restrict__ pair_slot, const float* __restrict__ tok_g)
{
    int n = blockIdx.x, t = threadIdx.x;
    int s0 = pair_slot[2 * n], s1 = pair_slot[2 * n + 1];
    float g0 = tok_g[2 * n], g1 = tok_g[2 * n + 1];
    float4 a = ((const float4*)(eo + (size_t)s0 * NO))[t];
    float4 b = ((const float4*)(eo + (size_t)s1 * NO))[t];
    float4* yp = (float4*)(y + (size_t)n * NO) + t;
    float4 v = *yp;
    v.x += g0 * a.x + g1 * b.x;
    v.y += g0 * a.y + g1 * b.y;
    v.z += g0 * a.z + g1 * b.z;
    v.w += g0 * a.w + g1 * b.w;
    *yp = v;
}

extern "C" void kernel_launch(void* const* d_in, const int* in_sizes, int n_in,
                              void* d_out, int out_size, void* d_ws, size_t ws_size,
                              hipStream_t stream) {
    const float* x    = (const float*)d_in[0];
    const float* nw   = (const float*)d_in[6];
    const float* nb   = (const float*)d_in[7];
    const float* eps  = (const float*)d_in[8];
    const float* wg   = (const float*)d_in[9];
    const float* whw  = (const float*)d_in[10];
    const float* whb  = (const float*)d_in[11];
    const float* wow  = (const float*)d_in[12];
    const float* wob  = (const float*)d_in[13];
    const float* wout = (const float*)d_in[14];

    char* ws = (char*)d_ws;
    // workspace layout (bytes)
    unsigned short* xn_bf = (unsigned short*)(ws + 0);          //  8,388,608
    unsigned short* x_bf  = (unsigned short*)(ws + 8388608);    //  8,388,608
    unsigned short* wh_bf = (unsigned short*)(ws + 16777216);   // 33,554,432
    float*          eo    = (float*)(ws + 16777216);            // alias: used after gemm1 done
    unsigned short* wo_bf = (unsigned short*)(ws + 50331648);   // 33,554,432
    unsigned short* wt_bf = (unsigned short*)(ws + 83886080);   //  2,097,152
    unsigned short* hbuf  = (unsigned short*)(ws + 85983232);   // 33,554,432
    char* meta = ws + 119537664;
    int*   counts     = (int*)(meta + 0);
    int*   offsets    = (int*)(meta + 128);
    int*   tok_e      = (int*)(meta + 2048);
    float* tok_g      = (float*)(meta + 2048 + 32768);
    int*   rowsbuf    = (int*)(meta + 2048 + 65536);
    int*   pair_slot  = (int*)(meta + 2048 + 98304);

    float* y = (float*)d_out;
    float* out_tail = y + (size_t)N_TOK * NO;   // loss, then gate_fraction[8]

    ln_gate_kernel<<<N_TOK, 256, 0, stream>>>(x, nw, nb, eps, wg, xn_bf, x_bf,
                                              tok_e, tok_g);
    {
        int n4 = NE * NH * DIM / 4;   // 4,194,304 each (wh and wo same size)
        cvt2_bf16_kernel<<<2 * n4 / 256, 256, 0, stream>>>(whw, wh_bf, wow, wo_bf, n4);
    }
    transpose_cvt_kernel<<<dim3(NO / 32, DIM / 32), dim3(32, 32), 0, stream>>>(wout, wt_bf);
    route_kernel<<<NE, 256, 0, stream>>>(tok_e, tok_g, counts, offsets,
                                         rowsbuf, pair_slot, out_tail);
    gemm1_kernel<<<dim3(NH / 128, N_TOK / 128, NE), 256, 0, stream>>>(
        xn_bf, wh_bf, whb, rowsbuf, counts, offsets, hbuf);
    gemm2_kernel<<<dim3(NO / 64, N_TOK / 128, NE), 256, 0, stream>>>(
        hbuf, wo_bf, wob, counts, offsets, eo);
    gemm_res_kernel<<<dim3(NO / 128, N_TOK / 64), 256, 0, stream>>>(x_bf, wt_bf, y);
    combine_kernel<<<N_TOK, 256, 0, stream>>>(y, eo, pair_slot, tok_g);
}

// Round 5
// 383.405 us; speedup vs baseline: 1.7066x; 1.0148x over previous
//
#include <hip/hip_runtime.h>
#include <hip/hip_bf16.h>
#include <stdint.h>

// Problem constants (from reference setup_inputs)
#define N_TOK 4096
#define DIM   1024
#define NE    8
#define NH    2048
#define NO    1024

typedef __attribute__((ext_vector_type(8))) short bf16x8;
typedef __attribute__((ext_vector_type(16))) float f32x16;

__device__ inline unsigned short f2bf(float f) {
    unsigned u = __float_as_uint(f);
    u += 0x7fffu + ((u >> 16) & 1u);   // round-to-nearest-even
    return (unsigned short)(u >> 16);
}

__device__ inline void async_copy16(const void* g, void* l) {
    __builtin_amdgcn_global_load_lds(
        (const __attribute__((address_space(1))) void*)g,
        (__attribute__((address_space(3))) void*)l, 16, 0, 0);
}

// ---------------- fused layernorm + gating (NO atomics) ----------------
// one block (256 thr) per token row
__global__ __launch_bounds__(256) void ln_gate_kernel(
    const float* __restrict__ x, const float* __restrict__ nw,
    const float* __restrict__ nb, const float* __restrict__ eps_p,
    const float* __restrict__ wg,
    unsigned short* __restrict__ xn_bf, unsigned short* __restrict__ x_bf,
    int* __restrict__ tok_e, float* __restrict__ tok_g)
{
    int n = blockIdx.x;
    int t = threadIdx.x;
    int lane = t & 63, wv = t >> 6;

    const float4 xv = ((const float4*)(x + (size_t)n * DIM))[t];
    float s  = xv.x + xv.y + xv.z + xv.w;
    float s2 = xv.x*xv.x + xv.y*xv.y + xv.z*xv.z + xv.w*xv.w;
    #pragma unroll
    for (int o = 32; o > 0; o >>= 1) {
        s  += __shfl_down(s, o);
        s2 += __shfl_down(s2, o);
    }
    __shared__ float rs[4], rs2[4];
    __shared__ float gred[4][NE];
    if (lane == 0) { rs[wv] = s; rs2[wv] = s2; }
    __syncthreads();
    float S  = rs[0] + rs[1] + rs[2] + rs[3];
    float S2 = rs2[0] + rs2[1] + rs2[2] + rs2[3];
    const float inv = 1.0f / (float)DIM;
    float mu = S * inv;
    float var = fmaxf(S2 * inv - mu * mu, 0.0f);   // biased, like F.layer_norm
    float rstd = rsqrtf(var + eps_p[0]);

    float4 w4 = ((const float4*)nw)[t];
    float4 b4 = ((const float4*)nb)[t];
    float xn0 = (xv.x - mu) * rstd * w4.x + b4.x;
    float xn1 = (xv.y - mu) * rstd * w4.y + b4.y;
    float xn2 = (xv.z - mu) * rstd * w4.z + b4.z;
    float xn3 = (xv.w - mu) * rstd * w4.w + b4.w;

    ushort4 pn; pn.x = f2bf(xn0); pn.y = f2bf(xn1); pn.z = f2bf(xn2); pn.w = f2bf(xn3);
    ((ushort4*)(xn_bf + (size_t)n * DIM))[t] = pn;
    ushort4 px; px.x = f2bf(xv.x); px.y = f2bf(xv.y); px.z = f2bf(xv.z); px.w = f2bf(xv.w);
    ((ushort4*)(x_bf + (size_t)n * DIM))[t] = px;

    // gating logits: x_norm (fp32) @ w_gate [D][E]
    float acc[NE];
    #pragma unroll
    for (int e = 0; e < NE; ++e) acc[e] = 0.0f;
    float xns[4] = {xn0, xn1, xn2, xn3};
    const float4* wgp = (const float4*)(wg + (size_t)(4 * t) * NE);
    #pragma unroll
    for (int j = 0; j < 4; ++j) {
        float4 w0 = wgp[2 * j], w1 = wgp[2 * j + 1];
        float xj = xns[j];
        acc[0] += xj * w0.x; acc[1] += xj * w0.y; acc[2] += xj * w0.z; acc[3] += xj * w0.w;
        acc[4] += xj * w1.x; acc[5] += xj * w1.y; acc[6] += xj * w1.z; acc[7] += xj * w1.w;
    }
    #pragma unroll
    for (int o = 32; o > 0; o >>= 1) {
        #pragma unroll
        for (int e = 0; e < NE; ++e) acc[e] += __shfl_down(acc[e], o);
    }
    if (lane == 0) {
        #pragma unroll
        for (int e = 0; e < NE; ++e) gred[wv][e] = acc[e];
    }
    __syncthreads();
    if (t == 0) {
        float lg[NE];
        float nrm2 = 0.0f;
        #pragma unroll
        for (int e = 0; e < NE; ++e) {
            lg[e] = gred[0][e] + gred[1][e] + gred[2][e] + gred[3][e];
            nrm2 += lg[e] * lg[e];
        }
        float den = fmaxf(sqrtf(nrm2), 1e-12f);
        float linv = 1.0f / den;
        #pragma unroll
        for (int e = 0; e < NE; ++e) lg[e] *= linv;
        float mx = lg[0];
        #pragma unroll
        for (int e = 1; e < NE; ++e) mx = fmaxf(mx, lg[e]);
        float p[NE], ps = 0.0f;
        #pragma unroll
        for (int e = 0; e < NE; ++e) { p[e] = expf(lg[e] - mx); ps += p[e]; }
        float pinv = 1.0f / ps;
        #pragma unroll
        for (int e = 0; e < NE; ++e) p[e] *= pinv;
        // top-2, lowest-index wins ties (jax.lax.top_k semantics)
        int i0 = 0; float b0 = lg[0];
        #pragma unroll
        for (int e = 1; e < NE; ++e) if (lg[e] > b0) { b0 = lg[e]; i0 = e; }
        int i1 = -1; float b1 = -3.0e38f;
        #pragma unroll
        for (int e = 0; e < NE; ++e) if (e != i0 && lg[e] > b1) { b1 = lg[e]; i1 = e; }
        tok_e[2 * n] = i0; tok_e[2 * n + 1] = i1;
        tok_g[2 * n] = p[i0]; tok_g[2 * n + 1] = p[i1];
    }
}

// ---------------- loss helper ----------------
__device__ inline float cv_sq(const float* v) {
    float m = 0.0f;
    for (int e = 0; e < NE; ++e) m += v[e];
    m *= (1.0f / NE);
    float s = 0.0f;
    for (int e = 0; e < NE; ++e) { float d = v[e] - m; s += d * d; }
    s *= (1.0f / (NE - 1));          // ddof=1
    return s / (m * m + 1e-6f);
}

// ---------------- fused prep: weight cvt + transpose + routing ----------------
// blocks [0, CVT_BLK)           : fp32->bf16 of wh and wo (contiguous)
// blocks [CVT_BLK, CVT_BLK+1024): transpose+cvt of output_weight
// blocks [CVT_BLK+1024, +8)     : routing (histogram/offsets/loss/scatter);
//                                 blocks are independent (redundant histogram).
#define CVT_BLK 32768
__global__ __launch_bounds__(256) void prep_kernel(
    const float* __restrict__ whw, unsigned short* __restrict__ wh_bf,
    const float* __restrict__ wow, unsigned short* __restrict__ wo_bf,
    const float* __restrict__ wout, unsigned short* __restrict__ wt_bf,
    const int* __restrict__ tok_e, const float* __restrict__ tok_g,
    int* __restrict__ counts, int* __restrict__ offsets,
    int* __restrict__ rowsbuf, float* __restrict__ gatebuf,
    float* __restrict__ out_tail)
{
    __shared__ float tile[32][33];
    __shared__ int   sc[4][NE], sp[4][NE];
    __shared__ float sf[4][NE];
    __shared__ int   lcur[NE];

    int b = blockIdx.x, t = threadIdx.x;

    if (b < CVT_BLK) {
        // ---- bulk convert: 2 * 4,194,304 float4 groups ----
        const int n4each = NE * NH * DIM / 4;
        int i = b * 256 + t;
        const float4* s; ushort4* d; int j;
        if (i < n4each) { s = (const float4*)whw; d = (ushort4*)wh_bf; j = i; }
        else            { s = (const float4*)wow; d = (ushort4*)wo_bf; j = i - n4each; }
        float4 v = s[j];
        ushort4 o; o.x = f2bf(v.x); o.y = f2bf(v.y); o.z = f2bf(v.z); o.w = f2bf(v.w);
        d[j] = o;
        return;
    }
    if (b < CVT_BLK + 1024) {
        // ---- output_weight [D][O] -> bf16 [O][D], 32x32 tile ----
        int idx = b - CVT_BLK;
        int o0 = (idx & 31) * 32, d0 = (idx >> 5) * 32;
        int tx = t & 31, ty0 = t >> 5;      // 32 x 8 threads, 4 rows each
        #pragma unroll
        for (int k = 0; k < 4; ++k) {
            int ty = ty0 + k * 8;
            tile[ty][tx] = wout[(size_t)(d0 + ty) * NO + o0 + tx];
        }
        __syncthreads();
        #pragma unroll
        for (int k = 0; k < 4; ++k) {
            int ty = ty0 + k * 8;
            wt_bf[(size_t)(o0 + ty) * DIM + d0 + tx] = f2bf(tile[tx][ty]);
        }
        return;
    }

    // ---- routing: this block scatters chunk [rb*1024, rb*1024+1024) ----
    int rb = b - (CVT_BLK + 1024);
    int lane = t & 63, wv = t >> 6;       // 4 waves
    int chunk0 = rb * 1024;

    int lc[NE]; float li[NE];
    #pragma unroll
    for (int e = 0; e < NE; ++e) { lc[e] = 0; li[e] = 0.0f; }
    int base = t * 32;
    #pragma unroll
    for (int q = 0; q < 8; ++q) {
        int4 e4 = *(const int4*)(tok_e + base + q * 4);
        float4 g4 = *(const float4*)(tok_g + base + q * 4);
        lc[e4.x]++; li[e4.x] += g4.x;
        lc[e4.y]++; li[e4.y] += g4.y;
        lc[e4.z]++; li[e4.z] += g4.z;
        lc[e4.w]++; li[e4.w] += g4.w;
    }
    int prior_flag = (base + 32 <= chunk0) ? 1 : 0;   // stripes don't straddle chunks
    int lp[NE];
    #pragma unroll
    for (int e = 0; e < NE; ++e) lp[e] = prior_flag ? lc[e] : 0;

    #pragma unroll
    for (int o = 32; o > 0; o >>= 1) {
        #pragma unroll
        for (int e = 0; e < NE; ++e) {
            lc[e] += __shfl_down(lc[e], o);
            lp[e] += __shfl_down(lp[e], o);
            li[e] += __shfl_down(li[e], o);
        }
    }
    if (lane == 0) {
        #pragma unroll
        for (int e = 0; e < NE; ++e) { sc[wv][e] = lc[e]; sp[wv][e] = lp[e]; sf[wv][e] = li[e]; }
    }
    __syncthreads();
    if (t == 0) {
        int cnt[NE], pri[NE]; float imp[NE];
        for (int e = 0; e < NE; ++e) {
            cnt[e] = sc[0][e] + sc[1][e] + sc[2][e] + sc[3][e];
            pri[e] = sp[0][e] + sp[1][e] + sp[2][e] + sp[3][e];
            imp[e] = sf[0][e] + sf[1][e] + sf[2][e] + sf[3][e];
        }
        int off = 0;
        for (int e = 0; e < NE; ++e) {
            lcur[e] = off + pri[e];
            if (rb == 0) { counts[e] = cnt[e]; offsets[e] = off; }
            off += cnt[e];
        }
        if (rb == 0) {
            float lcf[NE], lif[NE];
            for (int e = 0; e < NE; ++e) { lcf[e] = (float)cnt[e]; lif[e] = imp[e]; }
            float tot = (float)off;
            out_tail[0] = 0.01f * (cv_sq(lif) + cv_sq(lcf));              // loss
            for (int e = 0; e < NE; ++e) out_tail[1 + e] = lcf[e] / tot;  // gate_fraction
        }
    }
    __syncthreads();

    int g0 = chunk0 + 4 * t;
    int4 e4 = *(const int4*)(tok_e + g0);
    float4 g4 = *(const float4*)(tok_g + g0);
    int s0 = atomicAdd(&lcur[e4.x], 1);
    int s1 = atomicAdd(&lcur[e4.y], 1);
    int s2 = atomicAdd(&lcur[e4.z], 1);
    int s3 = atomicAdd(&lcur[e4.w], 1);
    int tok0 = g0 >> 1;
    rowsbuf[s0] = tok0;     rowsbuf[s1] = tok0;
    rowsbuf[s2] = tok0 + 1; rowsbuf[s3] = tok0 + 1;
    gatebuf[s0] = g4.x; gatebuf[s1] = g4.y;
    gatebuf[s2] = g4.z; gatebuf[s3] = g4.w;
}

// ---------------- GEMM kernels (32x32x16 MFMA) ----------------
// LDS layout: [row][64 shorts]; logical 16B-slot s of row r stored at physical
// slot s ^ (r & 7) -> bank-balanced wave64 ds_read_b128. Staging XORs the
// global source column; global_load_lds LDS dest stays lane-contiguous (m104).
// Fragments (32x32x16 bf16): A/B lane: row lane&31, k=(lane>>5)*8+j;
// C/D: col=lane&31, row=(reg&3)+8*(reg>>2)+4*(lane>>5)  [m74/m101].
#define BK 64

// GEMM1: 128x128 tile, wave = 2x2 blocks of 32x32.
__global__ __launch_bounds__(256) void gemm1_kernel(
    const unsigned short* __restrict__ xn,   // [N][D] bf16
    const unsigned short* __restrict__ wh,   // [E][H][D] bf16
    const float* __restrict__ hb,            // [E][H]
    const int* __restrict__ rowsbuf,
    const int* __restrict__ counts, const int* __restrict__ offsets,
    unsigned short* __restrict__ hbuf)       // [2N][H] bf16
{
    int e = blockIdx.z;
    int count = counts[e];
    int tm = blockIdx.y, tn = blockIdx.x;
    if (tm * 128 >= count) return;
    int off = offsets[e];

    __shared__ alignas(16) short As[128 * BK];
    __shared__ alignas(16) short Bs[128 * BK];

    int t = threadIdx.x;
    int c = t & 7, rl = t >> 3;
    int csw = (c ^ (rl & 7)) * 8;            // swizzled source column (shorts)
    const unsigned short* aptr[4];
    const unsigned short* bptr[4];
    #pragma unroll
    for (int p = 0; p < 4; ++p) {
        int mrow = tm * 128 + p * 32 + rl;
        int mc = mrow < count ? mrow : count - 1;
        int token = rowsbuf[off + mc];
        aptr[p] = xn + (size_t)token * DIM;
        bptr[p] = wh + ((size_t)e * NH + tn * 128 + p * 32 + rl) * DIM;
    }

    int lane = t & 63, wvi = t >> 6;
    int wm = (wvi & 1) * 64, wn = (wvi >> 1) * 64;
    int l31 = lane & 31, h = lane >> 5, sw = l31 & 7;

    f32x16 acc[2][2];
    #pragma unroll
    for (int i = 0; i < 2; ++i)
        #pragma unroll
        for (int j = 0; j < 2; ++j) acc[i][j] = (f32x16)(0.0f);

    for (int kt = 0; kt < DIM / BK; ++kt) {
        int kb = kt * BK + csw;
        #pragma unroll
        for (int p = 0; p < 4; ++p)
            async_copy16(aptr[p] + kb, (char*)As + p * 4096 + t * 16);
        #pragma unroll
        for (int p = 0; p < 4; ++p)
            async_copy16(bptr[p] + kb, (char*)Bs + p * 4096 + t * 16);
        __syncthreads();
        #pragma unroll
        for (int ks = 0; ks < 4; ++ks) {
            int ph = ((ks * 2 + h) ^ sw) * 8;
            bf16x8 af[2], bfr[2];
            #pragma unroll
            for (int i = 0; i < 2; ++i)
                af[i] = *(const bf16x8*)&As[(wm + i * 32 + l31) * BK + ph];
            #pragma unroll
            for (int j = 0; j < 2; ++j)
                bfr[j] = *(const bf16x8*)&Bs[(wn + j * 32 + l31) * BK + ph];
            #pragma unroll
            for (int i = 0; i < 2; ++i)
                #pragma unroll
                for (int j = 0; j < 2; ++j)
                    acc[i][j] = __builtin_amdgcn_mfma_f32_32x32x16_bf16(af[i], bfr[j], acc[i][j], 0, 0, 0);
        }
        __syncthreads();
    }

    #pragma unroll
    for (int i = 0; i < 2; ++i) {
        #pragma unroll
        for (int j = 0; j < 2; ++j) {
            int col = tn * 128 + wn + j * 32 + l31;
            float bias = hb[e * NH + col];
            #pragma unroll
            for (int r = 0; r < 16; ++r) {
                int row_d = (r & 3) + 8 * (r >> 2) + 4 * h;
                int m = tm * 128 + wm + i * 32 + row_d;
                if (m < count) {
                    float v = acc[i][j][r] + bias;
                    v = v / (1.0f + __expf(-v));           // silu
                    hbuf[(size_t)(off + m) * NH + col] = f2bf(v);
                }
            }
        }
    }
}

// GEMM2: 128x64 tile, wave = 2x1 blocks of 32x32.
// Epilogue: y[token][col] += gate * (acc + bias)   (device-scope atomic fadd;
// gemm_res has already written the residual base in a prior launch).
__global__ __launch_bounds__(256) void gemm2_kernel(
    const unsigned short* __restrict__ hbuf,  // [2N][H] bf16
    const unsigned short* __restrict__ wo,    // [E][O][H] bf16
    const float* __restrict__ ob,             // [E][O]
    const int* __restrict__ counts, const int* __restrict__ offsets,
    const int* __restrict__ rowsbuf, const float* __restrict__ gatebuf,
    float* __restrict__ y)                    // [N][O] fp32
{
    int e = blockIdx.z;
    int count = counts[e];
    int tm = blockIdx.y, tn = blockIdx.x;
    if (tm * 128 >= count) return;
    int off = offsets[e];

    __shared__ alignas(16) short As[128 * BK];
    __shared__ alignas(16) short Bs[64 * BK];

    int t = threadIdx.x;
    int c = t & 7, rl = t >> 3;
    int csw = (c ^ (rl & 7)) * 8;
    const unsigned short* aptr[4];
    const unsigned short* bptr[2];
    #pragma unroll
    for (int p = 0; p < 4; ++p) {
        int mrow = tm * 128 + p * 32 + rl;
        int mc = mrow < count ? mrow : count - 1;
        aptr[p] = hbuf + (size_t)(off + mc) * NH;
    }
    #pragma unroll
    for (int p = 0; p < 2; ++p)
        bptr[p] = wo + ((size_t)e * NO + tn * 64 + p * 32 + rl) * NH;

    int lane = t & 63, wvi = t >> 6;
    int wm = (wvi & 1) * 64, wn = (wvi >> 1) * 32;
    int l31 = lane & 31, h = lane >> 5, sw = l31 & 7;

    f32x16 acc[2];
    #pragma unroll
    for (int i = 0; i < 2; ++i) acc[i] = (f32x16)(0.0f);

    for (int kt = 0; kt < NH / BK; ++kt) {
        int kb = kt * BK + csw;
        #pragma unroll
        for (int p = 0; p < 4; ++p)
            async_copy16(aptr[p] + kb, (char*)As + p * 4096 + t * 16);
        #pragma unroll
        for (int p = 0; p < 2; ++p)
            async_copy16(bptr[p] + kb, (char*)Bs + p * 4096 + t * 16);
        __syncthreads();
        #pragma unroll
        for (int ks = 0; ks < 4; ++ks) {
            int ph = ((ks * 2 + h) ^ sw) * 8;
            bf16x8 af[2], bfr;
            #pragma unroll
            for (int i = 0; i < 2; ++i)
                af[i] = *(const bf16x8*)&As[(wm + i * 32 + l31) * BK + ph];
            bfr = *(const bf16x8*)&Bs[(wn + l31) * BK + ph];
            #pragma unroll
            for (int i = 0; i < 2; ++i)
                acc[i] = __builtin_amdgcn_mfma_f32_32x32x16_bf16(af[i], bfr, acc[i], 0, 0, 0);
        }
        __syncthreads();
    }

    int col = tn * 64 + wn + l31;
    float bias = ob[e * NO + col];
    #pragma unroll
    for (int i = 0; i < 2; ++i) {
        #pragma unroll
        for (int r = 0; r < 16; ++r) {
            int row_d = (r & 3) + 8 * (r >> 2) + 4 * h;
            int m = tm * 128 + wm + i * 32 + row_d;
            if (m < count) {
                int slot = off + m;
                int token = rowsbuf[slot];          // broadcast within lane row-group
                float g = gatebuf[slot];
                __hip_atomic_fetch_add(&y[(size_t)token * NO + col],
                                       g * (acc[i][r] + bias),
                                       __ATOMIC_RELAXED, __HIP_MEMORY_SCOPE_AGENT);
            }
        }
    }
}

// Residual GEMM: 64x128 tile, wave = 1x2 blocks of 32x32. y = x_bf . woutT
__global__ __launch_bounds__(256) void gemm_res_kernel(
    const unsigned short* __restrict__ xb,   // [N][D] bf16
    const unsigned short* __restrict__ wt,   // [O][D] bf16
    float* __restrict__ y)                   // [N][O] fp32
{
    int tm = blockIdx.y, tn = blockIdx.x;
    __shared__ alignas(16) short As[64 * BK];
    __shared__ alignas(16) short Bs[128 * BK];

    int t = threadIdx.x;
    int c = t & 7, rl = t >> 3;
    int csw = (c ^ (rl & 7)) * 8;
    const unsigned short* aptr[2];
    const unsigned short* bptr[4];
    #pragma unroll
    for (int p = 0; p < 2; ++p)
        aptr[p] = xb + (size_t)(tm * 64 + p * 32 + rl) * DIM;
    #pragma unroll
    for (int p = 0; p < 4; ++p)
        bptr[p] = wt + (size_t)(tn * 128 + p * 32 + rl) * DIM;

    int lane = t & 63, wvi = t >> 6;
    int wm = (wvi & 1) * 32, wn = (wvi >> 1) * 64;
    int l31 = lane & 31, h = lane >> 5, sw = l31 & 7;

    f32x16 acc[2];
    #pragma unroll
    for (int j = 0; j < 2; ++j) acc[j] = (f32x16)(0.0f);

    for (int kt = 0; kt < DIM / BK; ++kt) {
        int kb = kt * BK + csw;
        #pragma unroll
        for (int p = 0; p < 2; ++p)
            async_copy16(aptr[p] + kb, (char*)As + p * 4096 + t * 16);
        #pragma unroll
        for (int p = 0; p < 4; ++p)
            async_copy16(bptr[p] + kb, (char*)Bs + p * 4096 + t * 16);
        __syncthreads();
        #pragma unroll
        for (int ks = 0; ks < 4; ++ks) {
            int ph = ((ks * 2 + h) ^ sw) * 8;
            bf16x8 af, bfr[2];
            af = *(const bf16x8*)&As[(wm + l31) * BK + ph];
            #pragma unroll
            for (int j = 0; j < 2; ++j)
                bfr[j] = *(const bf16x8*)&Bs[(wn + j * 32 + l31) * BK + ph];
            #pragma unroll
            for (int j = 0; j < 2; ++j)
                acc[j] = __builtin_amdgcn_mfma_f32_32x32x16_bf16(af, bfr[j], acc[j], 0, 0, 0);
        }
        __syncthreads();
    }

    #pragma unroll
    for (int j = 0; j < 2; ++j) {
        int col = tn * 128 + wn + j * 32 + l31;
        #pragma unroll
        for (int r = 0; r < 16; ++r) {
            int row_d = (r & 3) + 8 * (r >> 2) + 4 * h;
            int row = tm * 64 + wm + row_d;
            y[(size_t)row * NO + col] = acc[j][r];
        }
    }
}

extern "C" void kernel_launch(void* const* d_in, const int* in_sizes, int n_in,
                              void* d_out, int out_size, void* d_ws, size_t ws_size,
                              hipStream_t stream) {
    const float* x    = (const float*)d_in[0];
    const float* nw   = (const float*)d_in[6];
    const float* nb   = (const float*)d_in[7];
    const float* eps  = (const float*)d_in[8];
    const float* wg   = (const float*)d_in[9];
    const float* whw  = (const float*)d_in[10];
    const float* whb  = (const float*)d_in[11];
    const float* wow  = (const float*)d_in[12];
    const float* wob  = (const float*)d_in[13];
    const float* wout = (const float*)d_in[14];

    char* ws = (char*)d_ws;
    // workspace layout (bytes)
    unsigned short* xn_bf = (unsigned short*)(ws + 0);          //  8,388,608
    unsigned short* x_bf  = (unsigned short*)(ws + 8388608);    //  8,388,608
    unsigned short* wh_bf = (unsigned short*)(ws + 16777216);   // 33,554,432
    unsigned short* wo_bf = (unsigned short*)(ws + 50331648);   // 33,554,432
    unsigned short* wt_bf = (unsigned short*)(ws + 83886080);   //  2,097,152
    unsigned short* hbuf  = (unsigned short*)(ws + 85983232);   // 33,554,432
    char* meta = ws + 119537664;
    int*   counts     = (int*)(meta + 0);
    int*   offsets    = (int*)(meta + 128);
    int*   tok_e      = (int*)(meta + 2048);
    float* tok_g      = (float*)(meta + 2048 + 32768);
    int*   rowsbuf    = (int*)(meta + 2048 + 65536);
    float* gatebuf    = (float*)(meta + 2048 + 98304);

    float* y = (float*)d_out;
    float* out_tail = y + (size_t)N_TOK * NO;   // loss, then gate_fraction[8]

    ln_gate_kernel<<<N_TOK, 256, 0, stream>>>(x, nw, nb, eps, wg, xn_bf, x_bf,
                                              tok_e, tok_g);
    prep_kernel<<<CVT_BLK + 1024 + 8, 256, 0, stream>>>(
        whw, wh_bf, wow, wo_bf, wout, wt_bf,
        tok_e, tok_g, counts, offsets, rowsbuf, gatebuf, out_tail);
    gemm_res_kernel<<<dim3(NO / 128, N_TOK / 64), 256, 0, stream>>>(x_bf, wt_bf, y);
    gemm1_kernel<<<dim3(NH / 128, N_TOK / 128, NE), 256, 0, stream>>>(
        xn_bf, wh_bf, whb, rowsbuf, counts, offsets, hbuf);
    gemm2_kernel<<<dim3(NO / 64, N_TOK / 128, NE), 256, 0, stream>>>(
        hbuf, wo_bf, wob, counts, offsets, rowsbuf, gatebuf, y);
}